// Round 1
// baseline (957.131 us; speedup 1.0000x reference)
//
#include <hip/hip_runtime.h>
#include <hip/hip_bf16.h>
#include <cmath>

// ToyMultiHeadAttention: B=4 T=2048 C=2048 H=16 D=128, causal.
// Pipeline: f32->bf16 convert | 3x NT proj GEMM (V writes transposed) |
//           flash attention (exp2-domain online softmax) | NT out GEMM (f32).

#define DEV __device__ __forceinline__

typedef short short8 __attribute__((ext_vector_type(8)));
typedef float floatx4 __attribute__((ext_vector_type(4)));

// async global->LDS, 16B per lane; LDS dest must be uniform base + lane*16
#define LDS16(gp, lp)                                                        \
  __builtin_amdgcn_global_load_lds(                                          \
      (const __attribute__((address_space(1))) void*)(gp),                   \
      (__attribute__((address_space(3))) void*)(lp), 16, 0, 0)

DEV unsigned short f2bf(float f) {  // RNE f32->bf16 (inputs finite)
  unsigned u = __builtin_bit_cast(unsigned, f);
  u += 0x7fffu + ((u >> 16) & 1u);
  return (unsigned short)(u >> 16);
}

DEV floatx4 mfma16(short8 a, short8 b, floatx4 c) {
  return __builtin_amdgcn_mfma_f32_16x16x32_bf16(a, b, c, 0, 0, 0);
}

__global__ __launch_bounds__(256) void cvt_kernel(
    const float* __restrict__ in, unsigned short* __restrict__ out, int n4) {
  int stride = gridDim.x * blockDim.x;
  for (int i = blockIdx.x * blockDim.x + threadIdx.x; i < n4; i += stride) {
    float4 v = reinterpret_cast<const float4*>(in)[i];
    ushort4 o;
    o.x = f2bf(v.x); o.y = f2bf(v.y); o.z = f2bf(v.z); o.w = f2bf(v.w);
    reinterpret_cast<ushort4*>(out)[i] = o;
  }
}

// NT GEMM: out[M,N] = A[M,K] * Bw[N,K]^T + bias, m97 structure (128^2, BK=32)
// MODE 0: bf16 row-major out; MODE 1: bf16 transposed-V out [B,H,D,T]; MODE 2: f32 out
template <int MODE>
__global__ __launch_bounds__(256) void gemm_nt(
    const unsigned short* __restrict__ A, const unsigned short* __restrict__ Bw,
    const float* __restrict__ bias, void* __restrict__ outp,
    int M, int N, int K, float oscale) {
  __shared__ unsigned short lA[128 * 32];
  __shared__ unsigned short lB[128 * 32];
  const int t = threadIdx.x;
  const int l = t & 63;
  const int w = t >> 6;
  const int lr = l & 15, lg = l >> 4;
  const int nbn = N >> 7;
  const int nwg = gridDim.x;
  int bid = blockIdx.x;
  // XCD-aware swizzle (valid: grid % 8 == 0)
  int wg = ((nwg & 7) == 0) ? ((bid & 7) * (nwg >> 3) + (bid >> 3)) : bid;
  const int bm = wg / nbn, bn = wg % nbn;
  const int wr = (w >> 1) * 64, wc = (w & 1) * 64;

  floatx4 zero = {0.f, 0.f, 0.f, 0.f};
  floatx4 acc[4][4];
#pragma unroll
  for (int i = 0; i < 4; i++)
#pragma unroll
    for (int j = 0; j < 4; j++) acc[i][j] = zero;

  const unsigned short* aT = A + (size_t)bm * 128 * K;
  const unsigned short* bT = Bw + (size_t)bn * 128 * K;

  for (int kt = 0; kt < K; kt += 32) {
#pragma unroll
    for (int i = 0; i < 2; i++) {
      int c = t + i * 256;          // 512 chunks of 16B per tile
      int row = c >> 2, kc = c & 3;
      LDS16(aT + (size_t)row * K + kt + kc * 8, &lA[c * 8]);
      LDS16(bT + (size_t)row * K + kt + kc * 8, &lB[c * 8]);
    }
    __syncthreads();
    short8 aF[4], bF[4];
#pragma unroll
    for (int mi = 0; mi < 4; mi++)
      aF[mi] = *(const short8*)&lA[(wr + mi * 16 + lr) * 32 + lg * 8];
#pragma unroll
    for (int ni = 0; ni < 4; ni++)
      bF[ni] = *(const short8*)&lB[(wc + ni * 16 + lr) * 32 + lg * 8];
#pragma unroll
    for (int mi = 0; mi < 4; mi++)
#pragma unroll
      for (int ni = 0; ni < 4; ni++)
        acc[mi][ni] = mfma16(aF[mi], bF[ni], acc[mi][ni]);
    __syncthreads();
  }

#pragma unroll
  for (int ni = 0; ni < 4; ni++) {
    int gc = bn * 128 + wc + ni * 16 + lr;
    float bv = bias[gc];
#pragma unroll
    for (int mi = 0; mi < 4; mi++) {
      int gr0 = bm * 128 + wr + mi * 16 + lg * 4;
#pragma unroll
      for (int r = 0; r < 4; r++) {
        int gr = gr0 + r;
        float v = (acc[mi][ni][r] + bv) * oscale;
        if (MODE == 0) {
          ((unsigned short*)outp)[(size_t)gr * N + gc] = f2bf(v);
        } else if (MODE == 2) {
          ((float*)outp)[(size_t)gr * N + gc] = v;
        } else {  // V: out[b][h][d][t] = v at (row=b*T+t, col=h*128+d)
          int b = gr >> 11, tt = gr & 2047, h = gc >> 7, d = gc & 127;
          ((unsigned short*)outp)[((size_t)(b * 16 + h) << 18) + (d << 11) + tt] =
              f2bf(v);
        }
      }
    }
  }
}

// Causal flash attention. Grid: (qtile=16, bh=64). 4 waves x 32 Q-rows.
// Q pre-scaled by log2e/sqrt(D) -> softmax in exp2 domain.
__global__ __launch_bounds__(256) void attn_kernel(
    const unsigned short* __restrict__ Qp, const unsigned short* __restrict__ Kp,
    const unsigned short* __restrict__ Vt, unsigned short* __restrict__ Out) {
  constexpr int T = 2048, C = 2048;
  __shared__ unsigned short sM[16384];   // Q stage [128][128]; then K[64][128] + V[128][64]
  __shared__ unsigned short sP[4][2048]; // per-wave P [32][64], swizzled
  const int qt = blockIdx.x, bh = blockIdx.y;
  const int b = bh >> 4, h = bh & 15;
  const int t = threadIdx.x, l = t & 63, w = t >> 6;
  const int lr = l & 15, lg = l >> 4, l7 = l & 7;

  const unsigned short* Qg = Qp + (size_t)(b * T + qt * 128) * C + h * 128;
  const unsigned short* Kg = Kp + (size_t)(b * T) * C + h * 128;
  const unsigned short* Vg = Vt + ((size_t)bh << 18);  // [128][T]

  // ---- stage Q [128][128], load frags to regs, then reuse LDS ----
#pragma unroll
  for (int i = 0; i < 8; i++) {
    int c = t + i * 256;
    int row = c >> 4, cc = c & 15;
    LDS16(Qg + (size_t)row * C + cc * 8, &sM[c * 8]);
  }
  __syncthreads();
  const int qw = qt * 128 + w * 32;
  short8 qf[2][4];
#pragma unroll
  for (int mi = 0; mi < 2; mi++)
#pragma unroll
    for (int ks = 0; ks < 4; ks++)
      qf[mi][ks] =
          *(const short8*)&sM[(w * 32 + mi * 16 + lr) * 128 + ks * 32 + lg * 8];
  __syncthreads();

  floatx4 zero = {0.f, 0.f, 0.f, 0.f};
  floatx4 oacc[2][8];
#pragma unroll
  for (int i = 0; i < 2; i++)
#pragma unroll
    for (int j = 0; j < 8; j++) oacc[i][j] = zero;
  float mold[2][4], lsum[2][4];
#pragma unroll
  for (int i = 0; i < 2; i++)
#pragma unroll
    for (int r = 0; r < 4; r++) { mold[i][r] = -1e30f; lsum[i][r] = 0.f; }

  unsigned short* sK = sM;         // [64][128]
  unsigned short* sV = sM + 8192;  // [128][64] (V transposed: [d][k])
  const int ntile = 2 * qt + 2;
  for (int tile = 0; tile < ntile; tile++) {
    const int kbase = tile * 64;
    // stage K/V with pre-swizzled global source (chunk ^= row&7) so the
    // strided fragment reads below are bank-conflict-mitigated
#pragma unroll
    for (int i = 0; i < 4; i++) {
      int c = t + i * 256;
      int row = c >> 4, cc = c & 15;
      LDS16(Kg + (size_t)(kbase + row) * C + (cc ^ (row & 7)) * 8, &sK[c * 8]);
    }
#pragma unroll
    for (int i = 0; i < 4; i++) {
      int c = t + i * 256;
      int d = c >> 3, cc = c & 7;
      LDS16(Vg + (size_t)d * T + kbase + (cc ^ (d & 7)) * 8, &sV[c * 8]);
    }
    __syncthreads();
    if (kbase <= qw + 31) {
      // ---- S = Q K^T (exp2-domain, scale folded into Q) ----
      floatx4 sc[2][4];
#pragma unroll
      for (int i = 0; i < 2; i++)
#pragma unroll
        for (int j = 0; j < 4; j++) sc[i][j] = zero;
#pragma unroll
      for (int ks = 0; ks < 4; ks++) {
#pragma unroll
        for (int ni = 0; ni < 4; ni++) {
          int R = ni * 16 + lr;
          short8 bF = *(const short8*)&sK[R * 128 + ((ks * 4 + lg) ^ l7) * 8];
#pragma unroll
          for (int mi = 0; mi < 2; mi++)
            sc[mi][ni] = mfma16(qf[mi][ks], bF, sc[mi][ni]);
        }
      }
      // ---- causal mask (diagonal tiles only) ----
      if (kbase + 63 > qw) {
#pragma unroll
        for (int mi = 0; mi < 2; mi++)
#pragma unroll
          for (int ni = 0; ni < 4; ni++)
#pragma unroll
            for (int r = 0; r < 4; r++) {
              int col = kbase + ni * 16 + lr;
              int row = qw + mi * 16 + lg * 4 + r;
              if (col > row) sc[mi][ni][r] = -1e30f;
            }
      }
      // ---- online softmax ----
#pragma unroll
      for (int mi = 0; mi < 2; mi++) {
        float al[4], mn[4];
#pragma unroll
        for (int r = 0; r < 4; r++) {
          float x = fmaxf(fmaxf(sc[mi][0][r], sc[mi][1][r]),
                          fmaxf(sc[mi][2][r], sc[mi][3][r]));
          x = fmaxf(x, __shfl_xor(x, 1));
          x = fmaxf(x, __shfl_xor(x, 2));
          x = fmaxf(x, __shfl_xor(x, 4));
          x = fmaxf(x, __shfl_xor(x, 8));
          float m2 = fmaxf(mold[mi][r], x);
          al[r] = __builtin_amdgcn_exp2f(mold[mi][r] - m2);
          mold[mi][r] = m2;
          mn[r] = m2;
        }
        float rs[4] = {0.f, 0.f, 0.f, 0.f};
#pragma unroll
        for (int ni = 0; ni < 4; ni++)
#pragma unroll
          for (int r = 0; r < 4; r++) {
            float p = __builtin_amdgcn_exp2f(sc[mi][ni][r] - mn[r]);
            sc[mi][ni][r] = p;
            rs[r] += p;
          }
#pragma unroll
        for (int r = 0; r < 4; r++) {
          float s = rs[r];
          s += __shfl_xor(s, 1);
          s += __shfl_xor(s, 2);
          s += __shfl_xor(s, 4);
          s += __shfl_xor(s, 8);
          lsum[mi][r] = lsum[mi][r] * al[r] + s;
        }
#pragma unroll
        for (int ni = 0; ni < 8; ni++)
#pragma unroll
          for (int r = 0; r < 4; r++) oacc[mi][ni][r] *= al[r];
        // P -> bf16 -> swizzled per-wave LDS
#pragma unroll
        for (int ni = 0; ni < 4; ni++)
#pragma unroll
          for (int r = 0; r < 4; r++) {
            int rr = mi * 16 + lg * 4 + r;
            int ch = (ni * 2 + ((l >> 3) & 1)) ^ (rr & 7);
            sP[w][rr * 64 + ch * 8 + l7] = f2bf(sc[mi][ni][r]);
          }
      }
      // ---- O += P V ----
#pragma unroll
      for (int ks = 0; ks < 2; ks++) {
        short8 pf[2];
#pragma unroll
        for (int mi = 0; mi < 2; mi++)
          pf[mi] = *(const short8*)&sP[w][(mi * 16 + lr) * 64 +
                                          ((ks * 4 + lg) ^ l7) * 8];
#pragma unroll
        for (int ni = 0; ni < 8; ni++) {
          int d = ni * 16 + lr;
          short8 vF = *(const short8*)&sV[d * 64 + ((ks * 4 + lg) ^ l7) * 8];
#pragma unroll
          for (int mi = 0; mi < 2; mi++)
            oacc[mi][ni] = mfma16(pf[mi], vF, oacc[mi][ni]);
        }
      }
    }
    __syncthreads();
  }
  // ---- epilogue: O/l -> bf16 row-major [B*T, C] ----
  unsigned short* Og = Out + (size_t)(b * T + qw) * C + h * 128;
#pragma unroll
  for (int mi = 0; mi < 2; mi++) {
    float rl[4];
#pragma unroll
    for (int r = 0; r < 4; r++) rl[r] = 1.0f / lsum[mi][r];
#pragma unroll
    for (int ni = 0; ni < 8; ni++)
#pragma unroll
      for (int r = 0; r < 4; r++)
        Og[(size_t)(mi * 16 + lg * 4 + r) * C + ni * 16 + lr] =
            f2bf(oacc[mi][ni][r] * rl[r]);
  }
}

extern "C" void kernel_launch(void* const* d_in, const int* in_sizes, int n_in,
                              void* d_out, int out_size, void* d_ws,
                              size_t ws_size, hipStream_t stream) {
  const float* q = (const float*)d_in[0];
  const float* k = (const float*)d_in[1];
  const float* v = (const float*)d_in[2];
  const float* Wq = (const float*)d_in[3];
  const float* bq = (const float*)d_in[4];
  const float* Wk = (const float*)d_in[5];
  const float* bk = (const float*)d_in[6];
  const float* Wv = (const float*)d_in[7];
  const float* bv = (const float*)d_in[8];
  const float* Wo = (const float*)d_in[9];
  const float* bo = (const float*)d_in[10];

  const int B = 4, T = 2048, C = 2048;
  const size_t E = (size_t)B * T * C;   // 16,777,216
  const size_t WE = (size_t)C * C;      // 4,194,304  (4*WE == E)
  unsigned short* ws = (unsigned short*)d_ws;
  unsigned short* qb = ws;              // bf16 q       [E]
  unsigned short* kb = ws + E;          // bf16 k
  unsigned short* vb = ws + 2 * E;      // bf16 v
  unsigned short* wqb = ws + 3 * E;     // bf16 weights [WE] x4
  unsigned short* wkb = wqb + WE;
  unsigned short* wvb = wqb + 2 * WE;
  unsigned short* wob = wqb + 3 * WE;
  unsigned short* Qp = ws + 4 * E;      // projected Q (pre-scaled)
  unsigned short* Kp = ws + 5 * E;      // projected K
  unsigned short* Vtb = ws + 6 * E;     // projected V, [B,H,D,T]
  unsigned short* attn = qb;            // alias: qb dead after projections
  // total workspace: 7*E*2 = 234,881,024 bytes

  cvt_kernel<<<2048, 256, 0, stream>>>(q, qb, (int)(E / 4));
  cvt_kernel<<<2048, 256, 0, stream>>>(k, kb, (int)(E / 4));
  cvt_kernel<<<2048, 256, 0, stream>>>(v, vb, (int)(E / 4));
  cvt_kernel<<<1024, 256, 0, stream>>>(Wq, wqb, (int)(WE / 4));
  cvt_kernel<<<1024, 256, 0, stream>>>(Wk, wkb, (int)(WE / 4));
  cvt_kernel<<<1024, 256, 0, stream>>>(Wv, wvb, (int)(WE / 4));
  cvt_kernel<<<1024, 256, 0, stream>>>(Wo, wob, (int)(WE / 4));

  const int M = B * T, N = C, K = C;
  const int grid = (M / 128) * (N / 128);  // 1024
  const float qscale = 1.4426950408889634f / sqrtf(128.0f);  // log2e/sqrt(D)
  gemm_nt<0><<<grid, 256, 0, stream>>>(qb, wqb, bq, Qp, M, N, K, qscale);
  gemm_nt<0><<<grid, 256, 0, stream>>>(kb, wkb, bk, Kp, M, N, K, 1.0f);
  gemm_nt<1><<<grid, 256, 0, stream>>>(vb, wvb, bv, Vtb, M, N, K, 1.0f);

  attn_kernel<<<dim3(16, 64), 256, 0, stream>>>(Qp, Kp, Vtb, attn);

  gemm_nt<2><<<grid, 256, 0, stream>>>(attn, wob, bo, d_out, M, N, K, 1.0f);
}

// Round 2
// 742.719 us; speedup vs baseline: 1.2887x; 1.2887x over previous
//
#include <hip/hip_runtime.h>
#include <hip/hip_bf16.h>
#include <cmath>

// ToyMultiHeadAttention: B=4 T=2048 C=2048 H=16 D=128, causal.
// Pipeline: f32->bf16 convert | 3x NT proj GEMM (V writes transposed) |
//           flash attention (dbuf prefetch, exp2 online softmax, defer-max) |
//           NT out GEMM (f32).

#define DEV __device__ __forceinline__

typedef short short8 __attribute__((ext_vector_type(8)));
typedef float floatx4 __attribute__((ext_vector_type(4)));

// async global->LDS, 16B per lane; LDS dest must be uniform base + lane*16
#define LDS16(gp, lp)                                                        \
  __builtin_amdgcn_global_load_lds(                                          \
      (const __attribute__((address_space(1))) void*)(gp),                   \
      (__attribute__((address_space(3))) void*)(lp), 16, 0, 0)

DEV unsigned short f2bf(float f) {  // RNE f32->bf16 (inputs finite)
  unsigned u = __builtin_bit_cast(unsigned, f);
  u += 0x7fffu + ((u >> 16) & 1u);
  return (unsigned short)(u >> 16);
}

DEV floatx4 mfma16(short8 a, short8 b, floatx4 c) {
  return __builtin_amdgcn_mfma_f32_16x16x32_bf16(a, b, c, 0, 0, 0);
}

__global__ __launch_bounds__(256) void cvt_kernel(
    const float* __restrict__ in, unsigned short* __restrict__ out, int n4) {
  int stride = gridDim.x * blockDim.x;
  for (int i = blockIdx.x * blockDim.x + threadIdx.x; i < n4; i += stride) {
    float4 v = reinterpret_cast<const float4*>(in)[i];
    ushort4 o;
    o.x = f2bf(v.x); o.y = f2bf(v.y); o.z = f2bf(v.z); o.w = f2bf(v.w);
    reinterpret_cast<ushort4*>(out)[i] = o;
  }
}

// NT GEMM: out[M,N] = A[M,K] * Bw[N,K]^T + bias, m97 structure (128^2, BK=32)
// MODE 0: bf16 row-major out; MODE 1: bf16 transposed-V out [B,H,D,T]; MODE 2: f32 out
template <int MODE>
__global__ __launch_bounds__(256) void gemm_nt(
    const unsigned short* __restrict__ A, const unsigned short* __restrict__ Bw,
    const float* __restrict__ bias, void* __restrict__ outp,
    int M, int N, int K, float oscale) {
  __shared__ unsigned short lA[128 * 32];
  __shared__ unsigned short lB[128 * 32];
  const int t = threadIdx.x;
  const int l = t & 63;
  const int w = t >> 6;
  const int lr = l & 15, lg = l >> 4;
  const int nbn = N >> 7;
  const int nwg = gridDim.x;
  int bid = blockIdx.x;
  // XCD-aware swizzle (valid: grid % 8 == 0)
  int wg = ((nwg & 7) == 0) ? ((bid & 7) * (nwg >> 3) + (bid >> 3)) : bid;
  const int bm = wg / nbn, bn = wg % nbn;
  const int wr = (w >> 1) * 64, wc = (w & 1) * 64;

  floatx4 zero = {0.f, 0.f, 0.f, 0.f};
  floatx4 acc[4][4];
#pragma unroll
  for (int i = 0; i < 4; i++)
#pragma unroll
    for (int j = 0; j < 4; j++) acc[i][j] = zero;

  const unsigned short* aT = A + (size_t)bm * 128 * K;
  const unsigned short* bT = Bw + (size_t)bn * 128 * K;

  for (int kt = 0; kt < K; kt += 32) {
#pragma unroll
    for (int i = 0; i < 2; i++) {
      int c = t + i * 256;          // 512 chunks of 16B per tile
      int row = c >> 2, kc = c & 3;
      LDS16(aT + (size_t)row * K + kt + kc * 8, &lA[c * 8]);
      LDS16(bT + (size_t)row * K + kt + kc * 8, &lB[c * 8]);
    }
    __syncthreads();
    short8 aF[4], bF[4];
#pragma unroll
    for (int mi = 0; mi < 4; mi++)
      aF[mi] = *(const short8*)&lA[(wr + mi * 16 + lr) * 32 + lg * 8];
#pragma unroll
    for (int ni = 0; ni < 4; ni++)
      bF[ni] = *(const short8*)&lB[(wc + ni * 16 + lr) * 32 + lg * 8];
    __builtin_amdgcn_s_setprio(1);
#pragma unroll
    for (int mi = 0; mi < 4; mi++)
#pragma unroll
      for (int ni = 0; ni < 4; ni++)
        acc[mi][ni] = mfma16(aF[mi], bF[ni], acc[mi][ni]);
    __builtin_amdgcn_s_setprio(0);
    __syncthreads();
  }

#pragma unroll
  for (int ni = 0; ni < 4; ni++) {
    int gc = bn * 128 + wc + ni * 16 + lr;
    float bv = bias[gc];
#pragma unroll
    for (int mi = 0; mi < 4; mi++) {
      int gr0 = bm * 128 + wr + mi * 16 + lg * 4;
#pragma unroll
      for (int r = 0; r < 4; r++) {
        int gr = gr0 + r;
        float v = (acc[mi][ni][r] + bv) * oscale;
        if (MODE == 0) {
          ((unsigned short*)outp)[(size_t)gr * N + gc] = f2bf(v);
        } else if (MODE == 2) {
          ((float*)outp)[(size_t)gr * N + gc] = v;
        } else {  // V: out[b][h][d][t] = v at (row=b*T+t, col=h*128+d)
          int b = gr >> 11, tt = gr & 2047, h = gc >> 7, d = gc & 127;
          ((unsigned short*)outp)[((size_t)(b * 16 + h) << 18) + (d << 11) + tt] =
              f2bf(v);
        }
      }
    }
  }
}

// Causal flash attention. 1D grid 1024: XCD-chunked, heavy-qt-first, same-bh
// blocks grouped per XCD for K/V L2 reuse. 4 waves x 32 Q-rows, KVBLK=64.
// Q pre-scaled by log2e/sqrt(D) -> softmax in exp2 domain. Double-buffered
// K/V prefetch (2-phase); defer-max rescale skip (THR=8).
__global__ __launch_bounds__(256, 2) void attn_kernel(
    const unsigned short* __restrict__ Qp, const unsigned short* __restrict__ Kp,
    const unsigned short* __restrict__ Vt, unsigned short* __restrict__ Out) {
  constexpr int T = 2048, C = 2048;
  // LDS: K dbuf [2][64][128], V dbuf [2][128][64], P [4][32][64] = 80 KiB
  __shared__ unsigned short lds[40960];
  unsigned short* sP = lds + 32768;

  const int bid = blockIdx.x;
  const int swz = (bid & 7) * 128 + (bid >> 3);  // bijective, 1024 % 8 == 0
  const int bh = swz >> 4;
  const int qt = 15 - (swz & 15);                // heavy tiles first
  const int b = bh >> 4, h = bh & 15;
  const int t = threadIdx.x, l = t & 63, w = t >> 6;
  const int lr = l & 15, lg = l >> 4, l7 = l & 7;

  const unsigned short* Qg = Qp + (size_t)(b * T + qt * 128) * C + h * 128;
  const unsigned short* Kg = Kp + (size_t)(b * T) * C + h * 128;
  const unsigned short* Vg = Vt + ((size_t)bh << 18);  // [128][T]

  // ---- stage Q [128][128] into lds[0..16383], frags to regs ----
#pragma unroll
  for (int i = 0; i < 8; i++) {
    int c = t + i * 256;
    int row = c >> 4, cc = c & 15;
    LDS16(Qg + (size_t)row * C + cc * 8, &lds[c * 8]);
  }
  __syncthreads();
  const int qw = qt * 128 + w * 32;
  short8 qf[2][4];
#pragma unroll
  for (int mi = 0; mi < 2; mi++)
#pragma unroll
    for (int ks = 0; ks < 4; ks++)
      qf[mi][ks] =
          *(const short8*)&lds[(w * 32 + mi * 16 + lr) * 128 + ks * 32 + lg * 8];
  __syncthreads();

  // K/V staging with pre-swizzled global source (chunk ^= row&7) so strided
  // fragment reads are bank-conflict-mitigated
  auto stage_kv = [&](int kb, int buf) {
    unsigned short* dK = lds + (buf ? 8192 : 0);
    unsigned short* dV = lds + 16384 + (buf ? 8192 : 0);
#pragma unroll
    for (int i = 0; i < 4; i++) {
      int c = t + i * 256;
      int row = c >> 4, cc = c & 15;
      LDS16(Kg + (size_t)(kb + row) * C + (cc ^ (row & 7)) * 8, &dK[c * 8]);
    }
#pragma unroll
    for (int i = 0; i < 4; i++) {
      int c = t + i * 256;
      int d = c >> 3, cc = c & 7;
      LDS16(Vg + (size_t)d * T + kb + (cc ^ (d & 7)) * 8, &dV[c * 8]);
    }
  };

  floatx4 zero = {0.f, 0.f, 0.f, 0.f};
  floatx4 oacc[2][8];
#pragma unroll
  for (int i = 0; i < 2; i++)
#pragma unroll
    for (int j = 0; j < 8; j++) oacc[i][j] = zero;
  float mold[2][4], lsum[2][4];
#pragma unroll
  for (int i = 0; i < 2; i++)
#pragma unroll
    for (int r = 0; r < 4; r++) { mold[i][r] = -1e30f; lsum[i][r] = 0.f; }

  const int ntile = 2 * qt + 2;
  stage_kv(0, 0);
  __syncthreads();
  int cur = 0;
  for (int tile = 0; tile < ntile; tile++) {
    const int kbase = tile * 64;
    if (tile + 1 < ntile) stage_kv(kbase + 64, cur ^ 1);  // async prefetch
    const unsigned short* sK = lds + (cur ? 8192 : 0);
    const unsigned short* sV = lds + 16384 + (cur ? 8192 : 0);
    if (kbase <= qw + 31) {
      // ---- S = Q K^T ----
      floatx4 sc[2][4];
#pragma unroll
      for (int i = 0; i < 2; i++)
#pragma unroll
        for (int j = 0; j < 4; j++) sc[i][j] = zero;
      __builtin_amdgcn_s_setprio(1);
#pragma unroll
      for (int ks = 0; ks < 4; ks++) {
#pragma unroll
        for (int ni = 0; ni < 4; ni++) {
          int R = ni * 16 + lr;
          short8 bF = *(const short8*)&sK[R * 128 + ((ks * 4 + lg) ^ l7) * 8];
#pragma unroll
          for (int mi = 0; mi < 2; mi++)
            sc[mi][ni] = mfma16(qf[mi][ks], bF, sc[mi][ni]);
        }
      }
      __builtin_amdgcn_s_setprio(0);
      // ---- causal mask (diagonal tiles only) ----
      if (kbase + 63 > qw) {
#pragma unroll
        for (int mi = 0; mi < 2; mi++)
#pragma unroll
          for (int ni = 0; ni < 4; ni++)
#pragma unroll
            for (int r = 0; r < 4; r++) {
              int col = kbase + ni * 16 + lr;
              int row = qw + mi * 16 + lg * 4 + r;
              if (col > row) sc[mi][ni][r] = -1e30f;
            }
      }
      // ---- online softmax (exp2 domain, defer-max THR=8) ----
#pragma unroll
      for (int mi = 0; mi < 2; mi++) {
        float xr[4];
        int dok = 1;
#pragma unroll
        for (int r = 0; r < 4; r++) {
          float x = fmaxf(fmaxf(sc[mi][0][r], sc[mi][1][r]),
                          fmaxf(sc[mi][2][r], sc[mi][3][r]));
          x = fmaxf(x, __shfl_xor(x, 1));
          x = fmaxf(x, __shfl_xor(x, 2));
          x = fmaxf(x, __shfl_xor(x, 4));
          x = fmaxf(x, __shfl_xor(x, 8));
          xr[r] = x;
          dok &= (x - mold[mi][r] <= 8.0f) ? 1 : 0;
        }
        const bool defer = __all(dok);  // wave-uniform
        float al[4];
        if (!defer) {
#pragma unroll
          for (int r = 0; r < 4; r++) {
            float m2 = fmaxf(mold[mi][r], xr[r]);
            al[r] = __builtin_amdgcn_exp2f(mold[mi][r] - m2);
            mold[mi][r] = m2;
          }
        }
        float rs[4] = {0.f, 0.f, 0.f, 0.f};
#pragma unroll
        for (int ni = 0; ni < 4; ni++)
#pragma unroll
          for (int r = 0; r < 4; r++) {
            float p = __builtin_amdgcn_exp2f(sc[mi][ni][r] - mold[mi][r]);
            sc[mi][ni][r] = p;
            rs[r] += p;
          }
#pragma unroll
        for (int r = 0; r < 4; r++) {
          float s = rs[r];
          s += __shfl_xor(s, 1);
          s += __shfl_xor(s, 2);
          s += __shfl_xor(s, 4);
          s += __shfl_xor(s, 8);
          rs[r] = s;
        }
        if (!defer) {
#pragma unroll
          for (int r = 0; r < 4; r++)
            lsum[mi][r] = lsum[mi][r] * al[r] + rs[r];
#pragma unroll
          for (int ni = 0; ni < 8; ni++)
#pragma unroll
            for (int r = 0; r < 4; r++) oacc[mi][ni][r] *= al[r];
        } else {
#pragma unroll
          for (int r = 0; r < 4; r++) lsum[mi][r] += rs[r];
        }
        // P -> bf16 -> swizzled per-wave LDS
#pragma unroll
        for (int ni = 0; ni < 4; ni++)
#pragma unroll
          for (int r = 0; r < 4; r++) {
            int rr = mi * 16 + lg * 4 + r;
            int ch = (ni * 2 + ((l >> 3) & 1)) ^ (rr & 7);
            sP[w * 2048 + rr * 64 + ch * 8 + l7] = f2bf(sc[mi][ni][r]);
          }
      }
      // ---- O += P V ----
      __builtin_amdgcn_s_setprio(1);
#pragma unroll
      for (int ks = 0; ks < 2; ks++) {
        short8 pf[2];
#pragma unroll
        for (int mi = 0; mi < 2; mi++)
          pf[mi] = *(const short8*)&sP[w * 2048 + (mi * 16 + lr) * 64 +
                                       ((ks * 4 + lg) ^ l7) * 8];
#pragma unroll
        for (int ni = 0; ni < 8; ni++) {
          int d = ni * 16 + lr;
          short8 vF = *(const short8*)&sV[d * 64 + ((ks * 4 + lg) ^ l7) * 8];
#pragma unroll
          for (int mi = 0; mi < 2; mi++)
            oacc[mi][ni] = mfma16(pf[mi], vF, oacc[mi][ni]);
        }
      }
      __builtin_amdgcn_s_setprio(0);
    }
    __syncthreads();  // drains prefetch vmcnt; next buffer ready
    cur ^= 1;
  }
  // ---- epilogue: O/l -> bf16 row-major [B*T, C] ----
  unsigned short* Og = Out + (size_t)(b * T + qw) * C + h * 128;
#pragma unroll
  for (int mi = 0; mi < 2; mi++) {
    float rl[4];
#pragma unroll
    for (int r = 0; r < 4; r++) rl[r] = 1.0f / lsum[mi][r];
#pragma unroll
    for (int ni = 0; ni < 8; ni++)
#pragma unroll
      for (int r = 0; r < 4; r++)
        Og[(size_t)(mi * 16 + lg * 4 + r) * C + ni * 16 + lr] =
            f2bf(oacc[mi][ni][r] * rl[r]);
  }
}

extern "C" void kernel_launch(void* const* d_in, const int* in_sizes, int n_in,
                              void* d_out, int out_size, void* d_ws,
                              size_t ws_size, hipStream_t stream) {
  const float* q = (const float*)d_in[0];
  const float* k = (const float*)d_in[1];
  const float* v = (const float*)d_in[2];
  const float* Wq = (const float*)d_in[3];
  const float* bq = (const float*)d_in[4];
  const float* Wk = (const float*)d_in[5];
  const float* bk = (const float*)d_in[6];
  const float* Wv = (const float*)d_in[7];
  const float* bv = (const float*)d_in[8];
  const float* Wo = (const float*)d_in[9];
  const float* bo = (const float*)d_in[10];

  const int B = 4, T = 2048, C = 2048;
  const size_t E = (size_t)B * T * C;   // 16,777,216
  const size_t WE = (size_t)C * C;      // 4,194,304  (4*WE == E)
  unsigned short* ws = (unsigned short*)d_ws;
  unsigned short* qb = ws;              // bf16 q       [E]
  unsigned short* kb = ws + E;          // bf16 k
  unsigned short* vb = ws + 2 * E;      // bf16 v
  unsigned short* wqb = ws + 3 * E;     // bf16 weights [WE] x4
  unsigned short* wkb = wqb + WE;
  unsigned short* wvb = wqb + 2 * WE;
  unsigned short* wob = wqb + 3 * WE;
  unsigned short* Qp = ws + 4 * E;      // projected Q (pre-scaled)
  unsigned short* Kp = ws + 5 * E;      // projected K
  unsigned short* Vtb = ws + 6 * E;     // projected V, [B,H,D,T]
  unsigned short* attn = qb;            // alias: qb dead after projections
  // total workspace: 7*E*2 = 234,881,024 bytes

  cvt_kernel<<<2048, 256, 0, stream>>>(q, qb, (int)(E / 4));
  cvt_kernel<<<2048, 256, 0, stream>>>(k, kb, (int)(E / 4));
  cvt_kernel<<<2048, 256, 0, stream>>>(v, vb, (int)(E / 4));
  cvt_kernel<<<1024, 256, 0, stream>>>(Wq, wqb, (int)(WE / 4));
  cvt_kernel<<<1024, 256, 0, stream>>>(Wk, wkb, (int)(WE / 4));
  cvt_kernel<<<1024, 256, 0, stream>>>(Wv, wvb, (int)(WE / 4));
  cvt_kernel<<<1024, 256, 0, stream>>>(Wo, wob, (int)(WE / 4));

  const int M = B * T, N = C, K = C;
  const int grid = (M / 128) * (N / 128);  // 1024
  const float qscale = 1.4426950408889634f / sqrtf(128.0f);  // log2e/sqrt(D)
  gemm_nt<0><<<grid, 256, 0, stream>>>(qb, wqb, bq, Qp, M, N, K, qscale);
  gemm_nt<0><<<grid, 256, 0, stream>>>(kb, wkb, bk, Kp, M, N, K, 1.0f);
  gemm_nt<1><<<grid, 256, 0, stream>>>(vb, wvb, bv, Vtb, M, N, K, 1.0f);

  attn_kernel<<<1024, 256, 0, stream>>>(Qp, Kp, Vtb, attn);

  gemm_nt<2><<<grid, 256, 0, stream>>>(attn, wob, bo, d_out, M, N, K, 1.0f);
}

// Round 3
// 646.999 us; speedup vs baseline: 1.4793x; 1.1479x over previous
//
#include <hip/hip_runtime.h>
#include <hip/hip_bf16.h>
#include <cmath>

// ToyMultiHeadAttention: B=4 T=2048 C=2048 H=16 D=128, causal.
// Pipeline: fused f32->bf16 convert (1 launch) | fused 3x NT proj GEMM
//           (V writes transposed) | balanced paired flash attention |
//           NT out GEMM (f32).

#define DEV __device__ __forceinline__

typedef short short8 __attribute__((ext_vector_type(8)));
typedef float floatx4 __attribute__((ext_vector_type(4)));

// async global->LDS, 16B per lane; LDS dest must be uniform base + lane*16
#define LDS16(gp, lp)                                                        \
  __builtin_amdgcn_global_load_lds(                                          \
      (const __attribute__((address_space(1))) void*)(gp),                   \
      (__attribute__((address_space(3))) void*)(lp), 16, 0, 0)

DEV unsigned short f2bf(float f) {  // RNE f32->bf16 (inputs finite)
  unsigned u = __builtin_bit_cast(unsigned, f);
  u += 0x7fffu + ((u >> 16) & 1u);
  return (unsigned short)(u >> 16);
}

DEV floatx4 mfma16(short8 a, short8 b, floatx4 c) {
  return __builtin_amdgcn_mfma_f32_16x16x32_bf16(a, b, c, 0, 0, 0);
}

struct Cvt7Args {
  const float* in[7];
  unsigned short* out[7];
  int n4[7];
};

__global__ __launch_bounds__(256) void cvt7_kernel(Cvt7Args a) {
  const int s = blockIdx.y;
  const float* __restrict__ in = a.in[s];
  unsigned short* __restrict__ out = a.out[s];
  const int n4 = a.n4[s];
  int stride = gridDim.x * blockDim.x;
  for (int i = blockIdx.x * blockDim.x + threadIdx.x; i < n4; i += stride) {
    float4 v = reinterpret_cast<const float4*>(in)[i];
    ushort4 o;
    o.x = f2bf(v.x); o.y = f2bf(v.y); o.z = f2bf(v.z); o.w = f2bf(v.w);
    reinterpret_cast<ushort4*>(out)[i] = o;
  }
}

// ---- fused 3-way projection GEMM: seg 0=Q(scaled) 1=K 2=V(transposed) ----
// out[M,N] = A[M,K] * W[N,K]^T + bias; m97 structure, 128^2 tile, BK=32.
// M=8192, N=K=2048; grid = 3*1024.
__global__ __launch_bounds__(256) void gemm_proj3(
    const unsigned short* __restrict__ qb, const unsigned short* __restrict__ kb,
    const unsigned short* __restrict__ vb, const unsigned short* __restrict__ wqb,
    const unsigned short* __restrict__ wkb, const unsigned short* __restrict__ wvb,
    const float* __restrict__ bq, const float* __restrict__ bk,
    const float* __restrict__ bv, unsigned short* __restrict__ Qp,
    unsigned short* __restrict__ Kp, unsigned short* __restrict__ Vt,
    float qscale) {
  constexpr int K = 2048, N = 2048;
  __shared__ unsigned short lA[128 * 32];
  __shared__ unsigned short lB[128 * 32];
  const int t = threadIdx.x;
  const int l = t & 63;
  const int w = t >> 6;
  const int lr = l & 15, lg = l >> 4;
  const int seg = blockIdx.x >> 10;          // 0,1,2
  const int inner = blockIdx.x & 1023;
  const int wg = (inner & 7) * 128 + (inner >> 3);  // XCD swizzle, 1024%8==0
  const int bm = wg >> 4, bn = wg & 15;
  const int wr = (w >> 1) * 64, wc = (w & 1) * 64;

  const unsigned short* A = (seg == 0) ? qb : (seg == 1) ? kb : vb;
  const unsigned short* Bw = (seg == 0) ? wqb : (seg == 1) ? wkb : wvb;
  const float* bias = (seg == 0) ? bq : (seg == 1) ? bk : bv;

  floatx4 zero = {0.f, 0.f, 0.f, 0.f};
  floatx4 acc[4][4];
#pragma unroll
  for (int i = 0; i < 4; i++)
#pragma unroll
    for (int j = 0; j < 4; j++) acc[i][j] = zero;

  const unsigned short* aT = A + (size_t)bm * 128 * K;
  const unsigned short* bT = Bw + (size_t)bn * 128 * K;

  for (int kt = 0; kt < K; kt += 32) {
#pragma unroll
    for (int i = 0; i < 2; i++) {
      int c = t + i * 256;
      int row = c >> 2, kc = c & 3;
      LDS16(aT + (size_t)row * K + kt + kc * 8, &lA[c * 8]);
      LDS16(bT + (size_t)row * K + kt + kc * 8, &lB[c * 8]);
    }
    __syncthreads();
    short8 aF[4], bF[4];
#pragma unroll
    for (int mi = 0; mi < 4; mi++)
      aF[mi] = *(const short8*)&lA[(wr + mi * 16 + lr) * 32 + lg * 8];
#pragma unroll
    for (int ni = 0; ni < 4; ni++)
      bF[ni] = *(const short8*)&lB[(wc + ni * 16 + lr) * 32 + lg * 8];
    __builtin_amdgcn_s_setprio(1);
#pragma unroll
    for (int mi = 0; mi < 4; mi++)
#pragma unroll
      for (int ni = 0; ni < 4; ni++)
        acc[mi][ni] = mfma16(aF[mi], bF[ni], acc[mi][ni]);
    __builtin_amdgcn_s_setprio(0);
    __syncthreads();
  }

  const float oscale = (seg == 0) ? qscale : 1.0f;
#pragma unroll
  for (int ni = 0; ni < 4; ni++) {
    int gc = bn * 128 + wc + ni * 16 + lr;
    float bvv = bias[gc];
#pragma unroll
    for (int mi = 0; mi < 4; mi++) {
      int gr0 = bm * 128 + wr + mi * 16 + lg * 4;
#pragma unroll
      for (int r = 0; r < 4; r++) {
        int gr = gr0 + r;
        float v = (acc[mi][ni][r] + bvv) * oscale;
        if (seg == 0) {
          Qp[(size_t)gr * N + gc] = f2bf(v);
        } else if (seg == 1) {
          Kp[(size_t)gr * N + gc] = f2bf(v);
        } else {  // V: out[b][h][d][t] at (row=b*T+t, col=h*128+d)
          int b = gr >> 11, tt = gr & 2047, h = gc >> 7, d = gc & 127;
          Vt[((size_t)(b * 16 + h) << 18) + (d << 11) + tt] = f2bf(v);
        }
      }
    }
  }
}

// NT GEMM f32-out for the output projection (m97 structure).
__global__ __launch_bounds__(256) void gemm_out(
    const unsigned short* __restrict__ A, const unsigned short* __restrict__ Bw,
    const float* __restrict__ bias, float* __restrict__ outp) {
  constexpr int K = 2048, N = 2048;
  __shared__ unsigned short lA[128 * 32];
  __shared__ unsigned short lB[128 * 32];
  const int t = threadIdx.x;
  const int l = t & 63;
  const int w = t >> 6;
  const int lr = l & 15, lg = l >> 4;
  const int inner = blockIdx.x;
  const int wg = (inner & 7) * 128 + (inner >> 3);
  const int bm = wg >> 4, bn = wg & 15;
  const int wr = (w >> 1) * 64, wc = (w & 1) * 64;

  floatx4 zero = {0.f, 0.f, 0.f, 0.f};
  floatx4 acc[4][4];
#pragma unroll
  for (int i = 0; i < 4; i++)
#pragma unroll
    for (int j = 0; j < 4; j++) acc[i][j] = zero;

  const unsigned short* aT = A + (size_t)bm * 128 * K;
  const unsigned short* bT = Bw + (size_t)bn * 128 * K;

  for (int kt = 0; kt < K; kt += 32) {
#pragma unroll
    for (int i = 0; i < 2; i++) {
      int c = t + i * 256;
      int row = c >> 2, kc = c & 3;
      LDS16(aT + (size_t)row * K + kt + kc * 8, &lA[c * 8]);
      LDS16(bT + (size_t)row * K + kt + kc * 8, &lB[c * 8]);
    }
    __syncthreads();
    short8 aF[4], bF[4];
#pragma unroll
    for (int mi = 0; mi < 4; mi++)
      aF[mi] = *(const short8*)&lA[(wr + mi * 16 + lr) * 32 + lg * 8];
#pragma unroll
    for (int ni = 0; ni < 4; ni++)
      bF[ni] = *(const short8*)&lB[(wc + ni * 16 + lr) * 32 + lg * 8];
    __builtin_amdgcn_s_setprio(1);
#pragma unroll
    for (int mi = 0; mi < 4; mi++)
#pragma unroll
      for (int ni = 0; ni < 4; ni++)
        acc[mi][ni] = mfma16(aF[mi], bF[ni], acc[mi][ni]);
    __builtin_amdgcn_s_setprio(0);
    __syncthreads();
  }

#pragma unroll
  for (int ni = 0; ni < 4; ni++) {
    int gc = bn * 128 + wc + ni * 16 + lr;
    float bvv = bias[gc];
#pragma unroll
    for (int mi = 0; mi < 4; mi++) {
      int gr0 = bm * 128 + wr + mi * 16 + lg * 4;
#pragma unroll
      for (int r = 0; r < 4; r++)
        outp[(size_t)(gr0 + r) * N + gc] = acc[mi][ni][r] + bvv;
    }
  }
}

// Causal flash attention, statically balanced: each block handles ONE bh and
// the q-tile PAIR (x, 15-x) -> uniform 34 tile-steps/block; grid 512 = exact
// 2-blocks/CU residency (one generation, no tail). XCD-chunked swizzle keeps
// same-bh blocks on one XCD for K/V L2 reuse. 4 waves x 32 Q-rows, KVBLK=64,
// dbuf K/V prefetch, exp2-domain online softmax with defer-max (THR=8).
__global__ __launch_bounds__(256, 2) void attn_kernel(
    const unsigned short* __restrict__ Qp, const unsigned short* __restrict__ Kp,
    const unsigned short* __restrict__ Vt, unsigned short* __restrict__ Out) {
  constexpr int T = 2048, C = 2048;
  // LDS: K dbuf [2][64][128], V dbuf [2][128][64], P [4][32][64] = 80 KiB
  __shared__ unsigned short lds[40960];
  unsigned short* sP = lds + 32768;

  const int bid = blockIdx.x;
  const int swz = (bid & 7) * 64 + (bid >> 3);  // bijective, 512 % 8 == 0
  const int bh = swz >> 3;
  const int pr = swz & 7;                       // pair index
  const int b = bh >> 4, h = bh & 15;
  const int t = threadIdx.x, l = t & 63, w = t >> 6;
  const int lr = l & 15, lg = l >> 4, l7 = l & 7;

  const unsigned short* Kg = Kp + (size_t)(b * T) * C + h * 128;
  const unsigned short* Vg = Vt + ((size_t)bh << 18);  // [128][T]

  // K/V staging with pre-swizzled global source (chunk ^= row&7) so strided
  // fragment reads are bank-conflict-mitigated
  auto stage_kv = [&](int kb, int buf) {
    unsigned short* dK = lds + (buf ? 8192 : 0);
    unsigned short* dV = lds + 16384 + (buf ? 8192 : 0);
#pragma unroll
    for (int i = 0; i < 4; i++) {
      int c = t + i * 256;
      int row = c >> 4, cc = c & 15;
      LDS16(Kg + (size_t)(kb + row) * C + (cc ^ (row & 7)) * 8, &dK[c * 8]);
    }
#pragma unroll
    for (int i = 0; i < 4; i++) {
      int c = t + i * 256;
      int d = c >> 3, cc = c & 7;
      LDS16(Vg + (size_t)d * T + kb + (cc ^ (d & 7)) * 8, &dV[c * 8]);
    }
  };

  for (int seg = 0; seg < 2; seg++) {
    const int qt = seg ? pr : 15 - pr;  // heavy tile first
    const unsigned short* Qg = Qp + (size_t)(b * T + qt * 128) * C + h * 128;

    // ---- stage Q [128][128] into lds[0..16383], frags to regs ----
#pragma unroll
    for (int i = 0; i < 8; i++) {
      int c = t + i * 256;
      int row = c >> 4, cc = c & 15;
      LDS16(Qg + (size_t)row * C + cc * 8, &lds[c * 8]);
    }
    __syncthreads();
    const int qw = qt * 128 + w * 32;
    short8 qf[2][4];
#pragma unroll
    for (int mi = 0; mi < 2; mi++)
#pragma unroll
      for (int ks = 0; ks < 4; ks++)
        qf[mi][ks] = *(const short8*)&lds[(w * 32 + mi * 16 + lr) * 128 +
                                          ks * 32 + lg * 8];
    __syncthreads();  // all qf reads done before K staging overwrites

    floatx4 zero = {0.f, 0.f, 0.f, 0.f};
    floatx4 oacc[2][8];
#pragma unroll
    for (int i = 0; i < 2; i++)
#pragma unroll
      for (int j = 0; j < 8; j++) oacc[i][j] = zero;
    float mold[2][4], lsum[2][4];
#pragma unroll
    for (int i = 0; i < 2; i++)
#pragma unroll
      for (int r = 0; r < 4; r++) { mold[i][r] = -1e30f; lsum[i][r] = 0.f; }

    const int ntile = 2 * qt + 2;
    stage_kv(0, 0);
    __syncthreads();
    int cur = 0;
    for (int tile = 0; tile < ntile; tile++) {
      const int kbase = tile * 64;
      if (tile + 1 < ntile) stage_kv(kbase + 64, cur ^ 1);  // async prefetch
      const unsigned short* sK = lds + (cur ? 8192 : 0);
      const unsigned short* sV = lds + 16384 + (cur ? 8192 : 0);
      if (kbase <= qw + 31) {
        // ---- S = Q K^T ----
        floatx4 sc[2][4];
#pragma unroll
        for (int i = 0; i < 2; i++)
#pragma unroll
          for (int j = 0; j < 4; j++) sc[i][j] = zero;
        __builtin_amdgcn_s_setprio(1);
#pragma unroll
        for (int ks = 0; ks < 4; ks++) {
#pragma unroll
          for (int ni = 0; ni < 4; ni++) {
            int R = ni * 16 + lr;
            short8 bF = *(const short8*)&sK[R * 128 + ((ks * 4 + lg) ^ l7) * 8];
#pragma unroll
            for (int mi = 0; mi < 2; mi++)
              sc[mi][ni] = mfma16(qf[mi][ks], bF, sc[mi][ni]);
          }
        }
        __builtin_amdgcn_s_setprio(0);
        // ---- causal mask (diagonal tiles only) ----
        if (kbase + 63 > qw) {
#pragma unroll
          for (int mi = 0; mi < 2; mi++)
#pragma unroll
            for (int ni = 0; ni < 4; ni++)
#pragma unroll
              for (int r = 0; r < 4; r++) {
                int col = kbase + ni * 16 + lr;
                int row = qw + mi * 16 + lg * 4 + r;
                if (col > row) sc[mi][ni][r] = -1e30f;
              }
        }
        // ---- online softmax (exp2 domain, defer-max THR=8) ----
#pragma unroll
        for (int mi = 0; mi < 2; mi++) {
          float xr[4];
          int dok = 1;
#pragma unroll
          for (int r = 0; r < 4; r++) {
            float x = fmaxf(fmaxf(sc[mi][0][r], sc[mi][1][r]),
                            fmaxf(sc[mi][2][r], sc[mi][3][r]));
            x = fmaxf(x, __shfl_xor(x, 1));
            x = fmaxf(x, __shfl_xor(x, 2));
            x = fmaxf(x, __shfl_xor(x, 4));
            x = fmaxf(x, __shfl_xor(x, 8));
            xr[r] = x;
            dok &= (x - mold[mi][r] <= 8.0f) ? 1 : 0;
          }
          const bool defer = __all(dok);  // wave-uniform
          float al[4];
          if (!defer) {
#pragma unroll
            for (int r = 0; r < 4; r++) {
              float m2 = fmaxf(mold[mi][r], xr[r]);
              al[r] = __builtin_amdgcn_exp2f(mold[mi][r] - m2);
              mold[mi][r] = m2;
            }
          }
          float rs[4] = {0.f, 0.f, 0.f, 0.f};
#pragma unroll
          for (int ni = 0; ni < 4; ni++)
#pragma unroll
            for (int r = 0; r < 4; r++) {
              float p = __builtin_amdgcn_exp2f(sc[mi][ni][r] - mold[mi][r]);
              sc[mi][ni][r] = p;
              rs[r] += p;
            }
#pragma unroll
          for (int r = 0; r < 4; r++) {
            float s = rs[r];
            s += __shfl_xor(s, 1);
            s += __shfl_xor(s, 2);
            s += __shfl_xor(s, 4);
            s += __shfl_xor(s, 8);
            rs[r] = s;
          }
          if (!defer) {
#pragma unroll
            for (int r = 0; r < 4; r++)
              lsum[mi][r] = lsum[mi][r] * al[r] + rs[r];
#pragma unroll
            for (int ni = 0; ni < 8; ni++)
#pragma unroll
              for (int r = 0; r < 4; r++) oacc[mi][ni][r] *= al[r];
          } else {
#pragma unroll
            for (int r = 0; r < 4; r++) lsum[mi][r] += rs[r];
          }
          // P -> bf16 -> swizzled per-wave LDS
#pragma unroll
          for (int ni = 0; ni < 4; ni++)
#pragma unroll
            for (int r = 0; r < 4; r++) {
              int rr = mi * 16 + lg * 4 + r;
              int ch = (ni * 2 + ((l >> 3) & 1)) ^ (rr & 7);
              sP[w * 2048 + rr * 64 + ch * 8 + l7] = f2bf(sc[mi][ni][r]);
            }
        }
        // ---- O += P V ----
        __builtin_amdgcn_s_setprio(1);
#pragma unroll
        for (int ks = 0; ks < 2; ks++) {
          short8 pf[2];
#pragma unroll
          for (int mi = 0; mi < 2; mi++)
            pf[mi] = *(const short8*)&sP[w * 2048 + (mi * 16 + lr) * 64 +
                                         ((ks * 4 + lg) ^ l7) * 8];
#pragma unroll
          for (int ni = 0; ni < 8; ni++) {
            int d = ni * 16 + lr;
            short8 vF = *(const short8*)&sV[d * 64 + ((ks * 4 + lg) ^ l7) * 8];
#pragma unroll
            for (int mi = 0; mi < 2; mi++)
              oacc[mi][ni] = mfma16(pf[mi], vF, oacc[mi][ni]);
          }
        }
        __builtin_amdgcn_s_setprio(0);
      }
      __syncthreads();  // drains prefetch vmcnt; next buffer ready
      cur ^= 1;
    }
    // ---- epilogue: O/l -> bf16 row-major [B*T, C] ----
    unsigned short* Og = Out + (size_t)(b * T + qw) * C + h * 128;
#pragma unroll
    for (int mi = 0; mi < 2; mi++) {
      float rl[4];
#pragma unroll
      for (int r = 0; r < 4; r++) rl[r] = 1.0f / lsum[mi][r];
#pragma unroll
      for (int ni = 0; ni < 8; ni++)
#pragma unroll
        for (int r = 0; r < 4; r++)
          Og[(size_t)(mi * 16 + lg * 4 + r) * C + ni * 16 + lr] =
              f2bf(oacc[mi][ni][r] * rl[r]);
    }
    __syncthreads();  // epilogue done before next segment's Q staging
  }
}

extern "C" void kernel_launch(void* const* d_in, const int* in_sizes, int n_in,
                              void* d_out, int out_size, void* d_ws,
                              size_t ws_size, hipStream_t stream) {
  const float* q = (const float*)d_in[0];
  const float* k = (const float*)d_in[1];
  const float* v = (const float*)d_in[2];
  const float* Wq = (const float*)d_in[3];
  const float* bq = (const float*)d_in[4];
  const float* Wk = (const float*)d_in[5];
  const float* bk = (const float*)d_in[6];
  const float* Wv = (const float*)d_in[7];
  const float* bv = (const float*)d_in[8];
  const float* Wo = (const float*)d_in[9];
  const float* bo = (const float*)d_in[10];

  const int B = 4, T = 2048, C = 2048;
  const size_t E = (size_t)B * T * C;   // 16,777,216
  const size_t WE = (size_t)C * C;      // 4,194,304  (4*WE == E)
  unsigned short* ws = (unsigned short*)d_ws;
  unsigned short* qb = ws;              // bf16 q       [E]
  unsigned short* kb = ws + E;          // bf16 k
  unsigned short* vb = ws + 2 * E;      // bf16 v
  unsigned short* wqb = ws + 3 * E;     // bf16 weights [WE] x4
  unsigned short* wkb = wqb + WE;
  unsigned short* wvb = wqb + 2 * WE;
  unsigned short* wob = wqb + 3 * WE;
  unsigned short* Qp = ws + 4 * E;      // projected Q (pre-scaled)
  unsigned short* Kp = ws + 5 * E;      // projected K
  unsigned short* Vtb = ws + 6 * E;     // projected V, [B,H,D,T]
  unsigned short* attn = qb;            // alias: qb dead after projections
  // total workspace: 7*E*2 = 234,881,024 bytes

  Cvt7Args ca;
  ca.in[0] = q;  ca.out[0] = qb;  ca.n4[0] = (int)(E / 4);
  ca.in[1] = k;  ca.out[1] = kb;  ca.n4[1] = (int)(E / 4);
  ca.in[2] = v;  ca.out[2] = vb;  ca.n4[2] = (int)(E / 4);
  ca.in[3] = Wq; ca.out[3] = wqb; ca.n4[3] = (int)(WE / 4);
  ca.in[4] = Wk; ca.out[4] = wkb; ca.n4[4] = (int)(WE / 4);
  ca.in[5] = Wv; ca.out[5] = wvb; ca.n4[5] = (int)(WE / 4);
  ca.in[6] = Wo; ca.out[6] = wob; ca.n4[6] = (int)(WE / 4);
  cvt7_kernel<<<dim3(512, 7), 256, 0, stream>>>(ca);

  const float qscale = 1.4426950408889634f / sqrtf(128.0f);  // log2e/sqrt(D)
  gemm_proj3<<<3072, 256, 0, stream>>>(qb, kb, vb, wqb, wkb, wvb, bq, bk, bv,
                                       Qp, Kp, Vtb, qscale);

  attn_kernel<<<512, 256, 0, stream>>>(Qp, Kp, Vtb, attn);

  gemm_out<<<1024, 256, 0, stream>>>(attn, wob, bo, (float*)d_out);
}

// Round 4
// 542.112 us; speedup vs baseline: 1.7656x; 1.1935x over previous
//
#include <hip/hip_runtime.h>
#include <hip/hip_bf16.h>
#include <cmath>

// ToyMultiHeadAttention: B=4 T=2048 C=2048 H=16 D=128, causal.
// Pipeline: fused f32->bf16 convert | fused 3x NT proj GEMM (256^2 tile,
//           4-buffer counted-vmcnt pipeline, V writes transposed) |
//           balanced paired flash attention | NT out GEMM (256^2, f32 out).

#define DEV __device__ __forceinline__

typedef short short8 __attribute__((ext_vector_type(8)));
typedef float floatx4 __attribute__((ext_vector_type(4)));

// async global->LDS, 16B per lane; LDS dest must be uniform base + lane*16
#define LDS16(gp, lp)                                                        \
  __builtin_amdgcn_global_load_lds(                                          \
      (const __attribute__((address_space(1))) void*)(gp),                   \
      (__attribute__((address_space(3))) void*)(lp), 16, 0, 0)

DEV unsigned short f2bf(float f) {  // RNE f32->bf16 (inputs finite)
  unsigned u = __builtin_bit_cast(unsigned, f);
  u += 0x7fffu + ((u >> 16) & 1u);
  return (unsigned short)(u >> 16);
}

DEV floatx4 mfma16(short8 a, short8 b, floatx4 c) {
  return __builtin_amdgcn_mfma_f32_16x16x32_bf16(a, b, c, 0, 0, 0);
}

struct Cvt7Args {
  const float* in[7];
  unsigned short* out[7];
  int n4[7];
};

__global__ __launch_bounds__(256) void cvt7_kernel(Cvt7Args a) {
  const int s = blockIdx.y;
  const float* __restrict__ in = a.in[s];
  unsigned short* __restrict__ out = a.out[s];
  const int n4 = a.n4[s];
  int stride = gridDim.x * blockDim.x;
  for (int i = blockIdx.x * blockDim.x + threadIdx.x; i < n4; i += stride) {
    float4 v = reinterpret_cast<const float4*>(in)[i];
    ushort4 o;
    o.x = f2bf(v.x); o.y = f2bf(v.y); o.z = f2bf(v.z); o.w = f2bf(v.w);
    reinterpret_cast<ushort4*>(out)[i] = o;
  }
}

// ============ 256^2-tile NT GEMM core: C[256,256] = A[256,K] * B[256,K]^T ===
// 512 threads = 8 waves (2M x 4N). BK=32. LDS: 4 buffers x (A 16KB + B 16KB)
// = 128 KiB. Stage distance 3 tiles; one s_barrier + counted vmcnt per tile.
// LDS chunk swizzle ch^=(row&3) applied on BOTH global source and ds_read.
// Race-freedom: stage(t+3) targets buf[(t-1)&3], dead since the boundary
// barrier after tile t-1 (all frag reads consumed by MFMAs before it).
// Boundary after tile t: vmcnt(8) = stages(t+2,t+3) outstanding => t+1 landed.
DEV void gemm256_core(const unsigned short* __restrict__ aT,
                      const unsigned short* __restrict__ bT,
                      unsigned short* lds, const int K, floatx4 (&acc)[8][4]) {
  const int t = threadIdx.x;
  const int l = t & 63;
  const int w = t >> 6;
  const int wm = w >> 2, wn = w & 3;
  const int lr = l & 15, lg = l >> 4;
  const int NT = K >> 5;  // requires NT >= 3

  // staging: A tile 256x32 = 1024 16B-chunks, 2 per thread; same for B.
  const int rA0 = t >> 2;
  const int chA0 = (t & 3) ^ (rA0 & 3);
  const int rA1 = (t + 512) >> 2;
  const int chA1 = (t & 3) ^ (rA1 & 3);

  auto stage = [&](int kt, int buf) {
    unsigned short* dst = lds + buf * 16384;
    const unsigned short* ga = aT + kt * 32;
    const unsigned short* gb = bT + kt * 32;
    LDS16(ga + (size_t)rA0 * K + chA0 * 8, dst + t * 8);
    LDS16(ga + (size_t)rA1 * K + chA1 * 8, dst + (t + 512) * 8);
    LDS16(gb + (size_t)rA0 * K + chA0 * 8, dst + 8192 + t * 8);
    LDS16(gb + (size_t)rA1 * K + chA1 * 8, dst + 8192 + (t + 512) * 8);
  };

  // prologue: tiles 0,1,2 in flight; wait tile 0 (oldest 4 of 12 loads)
  stage(0, 0);
  stage(1, 1);
  stage(2, 2);
  asm volatile("s_waitcnt vmcnt(8)" ::: "memory");
  __builtin_amdgcn_s_barrier();
  asm volatile("" ::: "memory");

  for (int tt = 0; tt < NT; ++tt) {
    const unsigned short* lA = lds + (tt & 3) * 16384;
    const unsigned short* lB = lA + 8192;
    if (tt + 3 < NT) stage(tt + 3, (tt + 3) & 3);  // into buf[(tt-1)&3]
    short8 aF[8], bF[4];
#pragma unroll
    for (int ni = 0; ni < 4; ni++) {
      int row = wn * 64 + ni * 16 + lr;
      bF[ni] = *(const short8*)&lB[row * 32 + ((lg ^ (row & 3)) * 8)];
    }
#pragma unroll
    for (int mi = 0; mi < 8; mi++) {
      int row = wm * 128 + mi * 16 + lr;
      aF[mi] = *(const short8*)&lA[row * 32 + ((lg ^ (row & 3)) * 8)];
    }
    __builtin_amdgcn_s_setprio(1);
#pragma unroll
    for (int mi = 0; mi < 8; mi++)
#pragma unroll
      for (int ni = 0; ni < 4; ni++)
        acc[mi][ni] = mfma16(aF[mi], bF[ni], acc[mi][ni]);
    __builtin_amdgcn_s_setprio(0);
    if (tt + 1 < NT) {  // boundary: ensure tile tt+1 resident for next iter
      if (tt + 4 <= NT)
        asm volatile("s_waitcnt vmcnt(8)" ::: "memory");
      else if (tt + 3 == NT)
        asm volatile("s_waitcnt vmcnt(4)" ::: "memory");
      else
        asm volatile("s_waitcnt vmcnt(0)" ::: "memory");
      __builtin_amdgcn_s_barrier();
      asm volatile("" ::: "memory");
    }
  }
}

// ---- fused 3-way projection GEMM: seg 0=Q(scaled) 1=K 2=V(transposed) ----
// M=8192, N=K=2048. Grid = 3 * 256 blocks of 512 threads.
__global__ __launch_bounds__(512, 2) void gemm256_proj3(
    const unsigned short* __restrict__ qb, const unsigned short* __restrict__ kb,
    const unsigned short* __restrict__ vb, const unsigned short* __restrict__ wqb,
    const unsigned short* __restrict__ wkb, const unsigned short* __restrict__ wvb,
    const float* __restrict__ bq, const float* __restrict__ bk,
    const float* __restrict__ bv, unsigned short* __restrict__ Qp,
    unsigned short* __restrict__ Kp, unsigned short* __restrict__ Vt,
    float qscale) {
  constexpr int K = 2048, N = 2048;
  __shared__ unsigned short lds[65536];  // 128 KiB
  const int seg = blockIdx.x >> 8;
  int inner = blockIdx.x & 255;
  inner = (inner & 7) * 32 + (inner >> 3);  // XCD swizzle, 256 % 8 == 0
  const int bm = inner >> 3, bn = inner & 7;

  const unsigned short* A = (seg == 0) ? qb : (seg == 1) ? kb : vb;
  const unsigned short* Bw = (seg == 0) ? wqb : (seg == 1) ? wkb : wvb;
  const float* bias = (seg == 0) ? bq : (seg == 1) ? bk : bv;

  floatx4 zero = {0.f, 0.f, 0.f, 0.f};
  floatx4 acc[8][4];
#pragma unroll
  for (int i = 0; i < 8; i++)
#pragma unroll
    for (int j = 0; j < 4; j++) acc[i][j] = zero;

  gemm256_core(A + (size_t)bm * 256 * K, Bw + (size_t)bn * 256 * K, lds, K, acc);

  const int t = threadIdx.x, l = t & 63, w = t >> 6;
  const int wm = w >> 2, wn = w & 3;
  const int lr = l & 15, lg = l >> 4;
  const float oscale = (seg == 0) ? qscale : 1.0f;
#pragma unroll
  for (int ni = 0; ni < 4; ni++) {
    int gc = bn * 256 + wn * 64 + ni * 16 + lr;
    float bvv = bias[gc];
#pragma unroll
    for (int mi = 0; mi < 8; mi++) {
      int gr0 = bm * 256 + wm * 128 + mi * 16 + lg * 4;
      if (seg == 2) {  // V transposed: [b][h][d][t], 4 consecutive t per lane
        int b = gr0 >> 11, tt0 = gr0 & 2047, h = gc >> 7, d = gc & 127;
        ushort4 v4;
        v4.x = f2bf(acc[mi][ni][0] + bvv);
        v4.y = f2bf(acc[mi][ni][1] + bvv);
        v4.z = f2bf(acc[mi][ni][2] + bvv);
        v4.w = f2bf(acc[mi][ni][3] + bvv);
        *(ushort4*)&Vt[((size_t)(b * 16 + h) << 18) + (d << 11) + tt0] = v4;
      } else {
        unsigned short* dst = (seg == 0) ? Qp : Kp;
#pragma unroll
        for (int r = 0; r < 4; r++)
          dst[(size_t)(gr0 + r) * N + gc] =
              f2bf((acc[mi][ni][r] + bvv) * oscale);
      }
    }
  }
}

// ---- output projection GEMM, f32 out. M=8192, N=K=2048, 256 blocks. ----
__global__ __launch_bounds__(512, 2) void gemm256_out(
    const unsigned short* __restrict__ A, const unsigned short* __restrict__ Bw,
    const float* __restrict__ bias, float* __restrict__ outp) {
  constexpr int K = 2048, N = 2048;
  __shared__ unsigned short lds[65536];
  int inner = blockIdx.x;
  inner = (inner & 7) * 32 + (inner >> 3);  // XCD swizzle, 256 % 8 == 0
  const int bm = inner >> 3, bn = inner & 7;

  floatx4 zero = {0.f, 0.f, 0.f, 0.f};
  floatx4 acc[8][4];
#pragma unroll
  for (int i = 0; i < 8; i++)
#pragma unroll
    for (int j = 0; j < 4; j++) acc[i][j] = zero;

  gemm256_core(A + (size_t)bm * 256 * K, Bw + (size_t)bn * 256 * K, lds, K, acc);

  const int t = threadIdx.x, l = t & 63, w = t >> 6;
  const int wm = w >> 2, wn = w & 3;
  const int lr = l & 15, lg = l >> 4;
#pragma unroll
  for (int ni = 0; ni < 4; ni++) {
    int gc = bn * 256 + wn * 64 + ni * 16 + lr;
    float bvv = bias[gc];
#pragma unroll
    for (int mi = 0; mi < 8; mi++) {
      int gr0 = bm * 256 + wm * 128 + mi * 16 + lg * 4;
#pragma unroll
      for (int r = 0; r < 4; r++)
        outp[(size_t)(gr0 + r) * N + gc] = acc[mi][ni][r] + bvv;
    }
  }
}

// Causal flash attention, statically balanced: each block handles ONE bh and
// the q-tile PAIR (x, 15-x) -> uniform 34 tile-steps/block; grid 512 = exact
// 2-blocks/CU residency. XCD-chunked swizzle keeps same-bh blocks on one XCD.
// 4 waves x 32 Q-rows, KVBLK=64, dbuf K/V prefetch, exp2-domain online
// softmax with defer-max (THR=8).
__global__ __launch_bounds__(256, 2) void attn_kernel(
    const unsigned short* __restrict__ Qp, const unsigned short* __restrict__ Kp,
    const unsigned short* __restrict__ Vt, unsigned short* __restrict__ Out) {
  constexpr int T = 2048, C = 2048;
  // LDS: K dbuf [2][64][128], V dbuf [2][128][64], P [4][32][64] = 80 KiB
  __shared__ unsigned short lds[40960];
  unsigned short* sP = lds + 32768;

  const int bid = blockIdx.x;
  const int swz = (bid & 7) * 64 + (bid >> 3);  // bijective, 512 % 8 == 0
  const int bh = swz >> 3;
  const int pr = swz & 7;                       // pair index
  const int b = bh >> 4, h = bh & 15;
  const int t = threadIdx.x, l = t & 63, w = t >> 6;
  const int lr = l & 15, lg = l >> 4, l7 = l & 7;

  const unsigned short* Kg = Kp + (size_t)(b * T) * C + h * 128;
  const unsigned short* Vg = Vt + ((size_t)bh << 18);  // [128][T]

  auto stage_kv = [&](int kb, int buf) {
    unsigned short* dK = lds + (buf ? 8192 : 0);
    unsigned short* dV = lds + 16384 + (buf ? 8192 : 0);
#pragma unroll
    for (int i = 0; i < 4; i++) {
      int c = t + i * 256;
      int row = c >> 4, cc = c & 15;
      LDS16(Kg + (size_t)(kb + row) * C + (cc ^ (row & 7)) * 8, &dK[c * 8]);
    }
#pragma unroll
    for (int i = 0; i < 4; i++) {
      int c = t + i * 256;
      int d = c >> 3, cc = c & 7;
      LDS16(Vg + (size_t)d * T + kb + (cc ^ (d & 7)) * 8, &dV[c * 8]);
    }
  };

  for (int seg = 0; seg < 2; seg++) {
    const int qt = seg ? pr : 15 - pr;  // heavy tile first
    const unsigned short* Qg = Qp + (size_t)(b * T + qt * 128) * C + h * 128;

#pragma unroll
    for (int i = 0; i < 8; i++) {
      int c = t + i * 256;
      int row = c >> 4, cc = c & 15;
      LDS16(Qg + (size_t)row * C + cc * 8, &lds[c * 8]);
    }
    __syncthreads();
    const int qw = qt * 128 + w * 32;
    short8 qf[2][4];
#pragma unroll
    for (int mi = 0; mi < 2; mi++)
#pragma unroll
      for (int ks = 0; ks < 4; ks++)
        qf[mi][ks] = *(const short8*)&lds[(w * 32 + mi * 16 + lr) * 128 +
                                          ks * 32 + lg * 8];
    __syncthreads();  // all qf reads done before K staging overwrites

    floatx4 zero = {0.f, 0.f, 0.f, 0.f};
    floatx4 oacc[2][8];
#pragma unroll
    for (int i = 0; i < 2; i++)
#pragma unroll
      for (int j = 0; j < 8; j++) oacc[i][j] = zero;
    float mold[2][4], lsum[2][4];
#pragma unroll
    for (int i = 0; i < 2; i++)
#pragma unroll
      for (int r = 0; r < 4; r++) { mold[i][r] = -1e30f; lsum[i][r] = 0.f; }

    const int ntile = 2 * qt + 2;
    stage_kv(0, 0);
    __syncthreads();
    int cur = 0;
    for (int tile = 0; tile < ntile; tile++) {
      const int kbase = tile * 64;
      if (tile + 1 < ntile) stage_kv(kbase + 64, cur ^ 1);  // async prefetch
      const unsigned short* sK = lds + (cur ? 8192 : 0);
      const unsigned short* sV = lds + 16384 + (cur ? 8192 : 0);
      if (kbase <= qw + 31) {
        // ---- S = Q K^T ----
        floatx4 sc[2][4];
#pragma unroll
        for (int i = 0; i < 2; i++)
#pragma unroll
          for (int j = 0; j < 4; j++) sc[i][j] = zero;
        __builtin_amdgcn_s_setprio(1);
#pragma unroll
        for (int ks = 0; ks < 4; ks++) {
#pragma unroll
          for (int ni = 0; ni < 4; ni++) {
            int R = ni * 16 + lr;
            short8 bF = *(const short8*)&sK[R * 128 + ((ks * 4 + lg) ^ l7) * 8];
#pragma unroll
            for (int mi = 0; mi < 2; mi++)
              sc[mi][ni] = mfma16(qf[mi][ks], bF, sc[mi][ni]);
          }
        }
        __builtin_amdgcn_s_setprio(0);
        // ---- causal mask (diagonal tiles only) ----
        if (kbase + 63 > qw) {
#pragma unroll
          for (int mi = 0; mi < 2; mi++)
#pragma unroll
            for (int ni = 0; ni < 4; ni++)
#pragma unroll
              for (int r = 0; r < 4; r++) {
                int col = kbase + ni * 16 + lr;
                int row = qw + mi * 16 + lg * 4 + r;
                if (col > row) sc[mi][ni][r] = -1e30f;
              }
        }
        // ---- online softmax (exp2 domain, defer-max THR=8) ----
#pragma unroll
        for (int mi = 0; mi < 2; mi++) {
          float xr[4];
          int dok = 1;
#pragma unroll
          for (int r = 0; r < 4; r++) {
            float x = fmaxf(fmaxf(sc[mi][0][r], sc[mi][1][r]),
                            fmaxf(sc[mi][2][r], sc[mi][3][r]));
            x = fmaxf(x, __shfl_xor(x, 1));
            x = fmaxf(x, __shfl_xor(x, 2));
            x = fmaxf(x, __shfl_xor(x, 4));
            x = fmaxf(x, __shfl_xor(x, 8));
            xr[r] = x;
            dok &= (x - mold[mi][r] <= 8.0f) ? 1 : 0;
          }
          const bool defer = __all(dok);  // wave-uniform
          float al[4];
          if (!defer) {
#pragma unroll
            for (int r = 0; r < 4; r++) {
              float m2 = fmaxf(mold[mi][r], xr[r]);
              al[r] = __builtin_amdgcn_exp2f(mold[mi][r] - m2);
              mold[mi][r] = m2;
            }
          }
          float rs[4] = {0.f, 0.f, 0.f, 0.f};
#pragma unroll
          for (int ni = 0; ni < 4; ni++)
#pragma unroll
            for (int r = 0; r < 4; r++) {
              float p = __builtin_amdgcn_exp2f(sc[mi][ni][r] - mold[mi][r]);
              sc[mi][ni][r] = p;
              rs[r] += p;
            }
#pragma unroll
          for (int r = 0; r < 4; r++) {
            float s = rs[r];
            s += __shfl_xor(s, 1);
            s += __shfl_xor(s, 2);
            s += __shfl_xor(s, 4);
            s += __shfl_xor(s, 8);
            rs[r] = s;
          }
          if (!defer) {
#pragma unroll
            for (int r = 0; r < 4; r++)
              lsum[mi][r] = lsum[mi][r] * al[r] + rs[r];
#pragma unroll
            for (int ni = 0; ni < 8; ni++)
#pragma unroll
              for (int r = 0; r < 4; r++) oacc[mi][ni][r] *= al[r];
          } else {
#pragma unroll
            for (int r = 0; r < 4; r++) lsum[mi][r] += rs[r];
          }
          // P -> bf16 -> swizzled per-wave LDS
#pragma unroll
          for (int ni = 0; ni < 4; ni++)
#pragma unroll
            for (int r = 0; r < 4; r++) {
              int rr = mi * 16 + lg * 4 + r;
              int ch = (ni * 2 + ((l >> 3) & 1)) ^ (rr & 7);
              sP[w * 2048 + rr * 64 + ch * 8 + l7] = f2bf(sc[mi][ni][r]);
            }
        }
        // ---- O += P V ----
        __builtin_amdgcn_s_setprio(1);
#pragma unroll
        for (int ks = 0; ks < 2; ks++) {
          short8 pf[2];
#pragma unroll
          for (int mi = 0; mi < 2; mi++)
            pf[mi] = *(const short8*)&sP[w * 2048 + (mi * 16 + lr) * 64 +
                                         ((ks * 4 + lg) ^ l7) * 8];
#pragma unroll
          for (int ni = 0; ni < 8; ni++) {
            int d = ni * 16 + lr;
            short8 vF = *(const short8*)&sV[d * 64 + ((ks * 4 + lg) ^ l7) * 8];
#pragma unroll
            for (int mi = 0; mi < 2; mi++)
              oacc[mi][ni] = mfma16(pf[mi], vF, oacc[mi][ni]);
          }
        }
        __builtin_amdgcn_s_setprio(0);
      }
      __syncthreads();  // drains prefetch vmcnt; next buffer ready
      cur ^= 1;
    }
    // ---- epilogue: O/l -> bf16 row-major [B*T, C] ----
    unsigned short* Og = Out + (size_t)(b * T + qw) * C + h * 128;
#pragma unroll
    for (int mi = 0; mi < 2; mi++) {
      float rl[4];
#pragma unroll
      for (int r = 0; r < 4; r++) rl[r] = 1.0f / lsum[mi][r];
#pragma unroll
      for (int ni = 0; ni < 8; ni++)
#pragma unroll
        for (int r = 0; r < 4; r++)
          Og[(size_t)(mi * 16 + lg * 4 + r) * C + ni * 16 + lr] =
              f2bf(oacc[mi][ni][r] * rl[r]);
    }
    __syncthreads();  // epilogue done before next segment's Q staging
  }
}

extern "C" void kernel_launch(void* const* d_in, const int* in_sizes, int n_in,
                              void* d_out, int out_size, void* d_ws,
                              size_t ws_size, hipStream_t stream) {
  const float* q = (const float*)d_in[0];
  const float* k = (const float*)d_in[1];
  const float* v = (const float*)d_in[2];
  const float* Wq = (const float*)d_in[3];
  const float* bq = (const float*)d_in[4];
  const float* Wk = (const float*)d_in[5];
  const float* bk = (const float*)d_in[6];
  const float* Wv = (const float*)d_in[7];
  const float* bv = (const float*)d_in[8];
  const float* Wo = (const float*)d_in[9];
  const float* bo = (const float*)d_in[10];

  const int B = 4, T = 2048, C = 2048;
  const size_t E = (size_t)B * T * C;   // 16,777,216
  const size_t WE = (size_t)C * C;      // 4,194,304
  unsigned short* ws = (unsigned short*)d_ws;
  unsigned short* qb = ws;              // bf16 q       [E]
  unsigned short* kb = ws + E;          // bf16 k
  unsigned short* vb = ws + 2 * E;      // bf16 v
  unsigned short* wqb = ws + 3 * E;     // bf16 weights [WE] x4
  unsigned short* wkb = wqb + WE;
  unsigned short* wvb = wqb + 2 * WE;
  unsigned short* wob = wqb + 3 * WE;
  unsigned short* Qp = ws + 4 * E;      // projected Q (pre-scaled)
  unsigned short* Kp = ws + 5 * E;      // projected K
  unsigned short* Vtb = ws + 6 * E;     // projected V, [B,H,D,T]
  unsigned short* attn = qb;            // alias: qb dead after projections
  // total workspace: 7*E*2 = 234,881,024 bytes

  Cvt7Args ca;
  ca.in[0] = q;  ca.out[0] = qb;  ca.n4[0] = (int)(E / 4);
  ca.in[1] = k;  ca.out[1] = kb;  ca.n4[1] = (int)(E / 4);
  ca.in[2] = v;  ca.out[2] = vb;  ca.n4[2] = (int)(E / 4);
  ca.in[3] = Wq; ca.out[3] = wqb; ca.n4[3] = (int)(WE / 4);
  ca.in[4] = Wk; ca.out[4] = wkb; ca.n4[4] = (int)(WE / 4);
  ca.in[5] = Wv; ca.out[5] = wvb; ca.n4[5] = (int)(WE / 4);
  ca.in[6] = Wo; ca.out[6] = wob; ca.n4[6] = (int)(WE / 4);
  cvt7_kernel<<<dim3(512, 7), 256, 0, stream>>>(ca);

  const float qscale = 1.4426950408889634f / sqrtf(128.0f);  // log2e/sqrt(D)
  gemm256_proj3<<<768, 512, 0, stream>>>(qb, kb, vb, wqb, wkb, wvb, bq, bk, bv,
                                         Qp, Kp, Vtb, qscale);

  attn_kernel<<<512, 256, 0, stream>>>(Qp, Kp, Vtb, attn);

  gemm256_out<<<256, 512, 0, stream>>>(attn, wob, bo, (float*)d_out);
}

// Round 5
// 531.383 us; speedup vs baseline: 1.8012x; 1.0202x over previous
//
#include <hip/hip_runtime.h>
#include <hip/hip_bf16.h>
#include <cmath>

// ToyMultiHeadAttention: B=4 T=2048 C=2048 H=16 D=128, causal.
// Pipeline: fused f32->bf16 convert | fused 3x NT proj GEMM (256^2 tile,
//           4-buffer counted-vmcnt pipeline, V writes transposed) |
//           balanced paired flash attention | NT out GEMM (256^2, f32 out).

#define DEV __device__ __forceinline__

typedef short short8 __attribute__((ext_vector_type(8)));
typedef float floatx4 __attribute__((ext_vector_type(4)));

// async global->LDS, 16B per lane; LDS dest must be uniform base + lane*16
#define LDS16(gp, lp)                                                        \
  __builtin_amdgcn_global_load_lds(                                          \
      (const __attribute__((address_space(1))) void*)(gp),                   \
      (__attribute__((address_space(3))) void*)(lp), 16, 0, 0)

DEV unsigned short f2bf(float f) {  // RNE f32->bf16 (inputs finite)
  unsigned u = __builtin_bit_cast(unsigned, f);
  u += 0x7fffu + ((u >> 16) & 1u);
  return (unsigned short)(u >> 16);
}

DEV floatx4 mfma16(short8 a, short8 b, floatx4 c) {
  return __builtin_amdgcn_mfma_f32_16x16x32_bf16(a, b, c, 0, 0, 0);
}

struct Cvt7Args {
  const float* in[7];
  unsigned short* out[7];
  int n4[7];
};

__global__ __launch_bounds__(256) void cvt7_kernel(Cvt7Args a) {
  const int s = blockIdx.y;
  const float* __restrict__ in = a.in[s];
  unsigned short* __restrict__ out = a.out[s];
  const int n4 = a.n4[s];
  int stride = gridDim.x * blockDim.x;
  for (int i = blockIdx.x * blockDim.x + threadIdx.x; i < n4; i += stride) {
    float4 v = reinterpret_cast<const float4*>(in)[i];
    ushort4 o;
    o.x = f2bf(v.x); o.y = f2bf(v.y); o.z = f2bf(v.z); o.w = f2bf(v.w);
    reinterpret_cast<ushort4*>(out)[i] = o;
  }
}

// ============ 256^2-tile NT GEMM core: C[256,256] = A[256,K] * B[256,K]^T ===
// 512 threads = 8 waves (2M x 4N). BK=32. LDS: 4 buffers x (A 16KB + B 16KB)
// = 128 KiB. Stage distance 3 tiles; one s_barrier + counted vmcnt per tile.
// LDS chunk swizzle ch ^= (row>>1)&3 applied on BOTH global source and
// ds_read (same involution). Bank math: byte = row*64 + ch*16 -> bank group
// = 16*(row&1) + 4*(ch ^ ((row>>1)&3)); (row&1,(row>>1)&3) is injective over
// 8 consecutive rows -> 2 lanes/bank-group -> conflict-free (2-way is free).
// Race-freedom: stage(t+3) targets buf[(t-1)&3], dead since the boundary
// barrier after tile t-1. Boundary after tile t: vmcnt(8) = stages(t+2,t+3)
// outstanding => stage(t+1) landed.
DEV void gemm256_core(const unsigned short* __restrict__ aT,
                      const unsigned short* __restrict__ bT,
                      unsigned short* lds, const int K, floatx4 (&acc)[8][4]) {
  const int t = threadIdx.x;
  const int l = t & 63;
  const int w = t >> 6;
  const int wm = w >> 2, wn = w & 3;
  const int lr = l & 15, lg = l >> 4;
  const int NT = K >> 5;  // requires NT >= 3

  // staging: A tile 256x32 = 1024 16B-chunks, 2 per thread; same for B.
  const int rA0 = t >> 2;
  const int chA0 = (t & 3) ^ ((rA0 >> 1) & 3);
  const int rA1 = (t + 512) >> 2;
  const int chA1 = (t & 3) ^ ((rA1 >> 1) & 3);

  auto stage = [&](int kt, int buf) {
    unsigned short* dst = lds + buf * 16384;
    const unsigned short* ga = aT + kt * 32;
    const unsigned short* gb = bT + kt * 32;
    LDS16(ga + (size_t)rA0 * K + chA0 * 8, dst + t * 8);
    LDS16(ga + (size_t)rA1 * K + chA1 * 8, dst + (t + 512) * 8);
    LDS16(gb + (size_t)rA0 * K + chA0 * 8, dst + 8192 + t * 8);
    LDS16(gb + (size_t)rA1 * K + chA1 * 8, dst + 8192 + (t + 512) * 8);
  };

  // prologue: tiles 0,1,2 in flight; wait tile 0 (oldest 4 of 12 loads)
  stage(0, 0);
  stage(1, 1);
  stage(2, 2);
  asm volatile("s_waitcnt vmcnt(8)" ::: "memory");
  __builtin_amdgcn_s_barrier();
  asm volatile("" ::: "memory");

  for (int tt = 0; tt < NT; ++tt) {
    const unsigned short* lA = lds + (tt & 3) * 16384;
    const unsigned short* lB = lA + 8192;
    if (tt + 3 < NT) stage(tt + 3, (tt + 3) & 3);  // into buf[(tt-1)&3]
    short8 aF[8], bF[4];
#pragma unroll
    for (int ni = 0; ni < 4; ni++) {
      int row = wn * 64 + ni * 16 + lr;
      bF[ni] = *(const short8*)&lB[row * 32 + ((lg ^ ((row >> 1) & 3)) * 8)];
    }
#pragma unroll
    for (int mi = 0; mi < 8; mi++) {
      int row = wm * 128 + mi * 16 + lr;
      aF[mi] = *(const short8*)&lA[row * 32 + ((lg ^ ((row >> 1) & 3)) * 8)];
    }
    __builtin_amdgcn_s_setprio(1);
#pragma unroll
    for (int mi = 0; mi < 8; mi++)
#pragma unroll
      for (int ni = 0; ni < 4; ni++)
        acc[mi][ni] = mfma16(aF[mi], bF[ni], acc[mi][ni]);
    __builtin_amdgcn_s_setprio(0);
    if (tt + 1 < NT) {  // boundary: ensure tile tt+1 resident for next iter
      if (tt + 4 <= NT)
        asm volatile("s_waitcnt vmcnt(8)" ::: "memory");
      else if (tt + 3 == NT)
        asm volatile("s_waitcnt vmcnt(4)" ::: "memory");
      else
        asm volatile("s_waitcnt vmcnt(0)" ::: "memory");
      __builtin_amdgcn_s_barrier();
      asm volatile("" ::: "memory");
    }
  }
}

// ---- fused 3-way projection GEMM: seg 0=Q(scaled) 1=K 2=V(transposed) ----
// M=8192, N=K=2048. Grid = 3 * 256 blocks of 512 threads.
__global__ __launch_bounds__(512, 2) void gemm256_proj3(
    const unsigned short* __restrict__ qb, const unsigned short* __restrict__ kb,
    const unsigned short* __restrict__ vb, const unsigned short* __restrict__ wqb,
    const unsigned short* __restrict__ wkb, const unsigned short* __restrict__ wvb,
    const float* __restrict__ bq, const float* __restrict__ bk,
    const float* __restrict__ bv, unsigned short* __restrict__ Qp,
    unsigned short* __restrict__ Kp, unsigned short* __restrict__ Vt,
    float qscale) {
  constexpr int K = 2048, N = 2048;
  __shared__ unsigned short lds[65536];  // 128 KiB
  const int seg = blockIdx.x >> 8;
  int inner = blockIdx.x & 255;
  inner = (inner & 7) * 32 + (inner >> 3);  // XCD swizzle, 256 % 8 == 0
  const int bm = inner >> 3, bn = inner & 7;

  const unsigned short* A = (seg == 0) ? qb : (seg == 1) ? kb : vb;
  const unsigned short* Bw = (seg == 0) ? wqb : (seg == 1) ? wkb : wvb;
  const float* bias = (seg == 0) ? bq : (seg == 1) ? bk : bv;

  floatx4 zero = {0.f, 0.f, 0.f, 0.f};
  floatx4 acc[8][4];
#pragma unroll
  for (int i = 0; i < 8; i++)
#pragma unroll
    for (int j = 0; j < 4; j++) acc[i][j] = zero;

  gemm256_core(A + (size_t)bm * 256 * K, Bw + (size_t)bn * 256 * K, lds, K, acc);

  const int t = threadIdx.x, l = t & 63, w = t >> 6;
  const int wm = w >> 2, wn = w & 3;
  const int lr = l & 15, lg = l >> 4;
  const float oscale = (seg == 0) ? qscale : 1.0f;
#pragma unroll
  for (int ni = 0; ni < 4; ni++) {
    int gc = bn * 256 + wn * 64 + ni * 16 + lr;
    float bvv = bias[gc];
#pragma unroll
    for (int mi = 0; mi < 8; mi++) {
      int gr0 = bm * 256 + wm * 128 + mi * 16 + lg * 4;
      if (seg == 2) {  // V transposed: [b][h][d][t], 4 consecutive t per lane
        int b = gr0 >> 11, tt0 = gr0 & 2047, h = gc >> 7, d = gc & 127;
        ushort4 v4;
        v4.x = f2bf(acc[mi][ni][0] + bvv);
        v4.y = f2bf(acc[mi][ni][1] + bvv);
        v4.z = f2bf(acc[mi][ni][2] + bvv);
        v4.w = f2bf(acc[mi][ni][3] + bvv);
        *(ushort4*)&Vt[((size_t)(b * 16 + h) << 18) + (d << 11) + tt0] = v4;
      } else {
        unsigned short* dst = (seg == 0) ? Qp : Kp;
#pragma unroll
        for (int r = 0; r < 4; r++)
          dst[(size_t)(gr0 + r) * N + gc] =
              f2bf((acc[mi][ni][r] + bvv) * oscale);
      }
    }
  }
}

// ---- output projection GEMM, f32 out. M=8192, N=K=2048, 256 blocks. ----
__global__ __launch_bounds__(512, 2) void gemm256_out(
    const unsigned short* __restrict__ A, const unsigned short* __restrict__ Bw,
    const float* __restrict__ bias, float* __restrict__ outp) {
  constexpr int K = 2048, N = 2048;
  __shared__ unsigned short lds[65536];
  int inner = blockIdx.x;
  inner = (inner & 7) * 32 + (inner >> 3);  // XCD swizzle, 256 % 8 == 0
  const int bm = inner >> 3, bn = inner & 7;

  floatx4 zero = {0.f, 0.f, 0.f, 0.f};
  floatx4 acc[8][4];
#pragma unroll
  for (int i = 0; i < 8; i++)
#pragma unroll
    for (int j = 0; j < 4; j++) acc[i][j] = zero;

  gemm256_core(A + (size_t)bm * 256 * K, Bw + (size_t)bn * 256 * K, lds, K, acc);

  const int t = threadIdx.x, l = t & 63, w = t >> 6;
  const int wm = w >> 2, wn = w & 3;
  const int lr = l & 15, lg = l >> 4;
#pragma unroll
  for (int ni = 0; ni < 4; ni++) {
    int gc = bn * 256 + wn * 64 + ni * 16 + lr;
    float bvv = bias[gc];
#pragma unroll
    for (int mi = 0; mi < 8; mi++) {
      int gr0 = bm * 256 + wm * 128 + mi * 16 + lg * 4;
#pragma unroll
      for (int r = 0; r < 4; r++)
        outp[(size_t)(gr0 + r) * N + gc] = acc[mi][ni][r] + bvv;
    }
  }
}

// Causal flash attention, statically balanced: each block handles ONE bh and
// the q-tile PAIR (x, 15-x) -> uniform 34 tile-steps/block; grid 512 = exact
// 2-blocks/CU residency. XCD-chunked swizzle keeps same-bh blocks on one XCD.
// 4 waves x 32 Q-rows, KVBLK=64, dbuf K/V prefetch, exp2-domain online
// softmax with defer-max (THR=8).
__global__ __launch_bounds__(256, 2) void attn_kernel(
    const unsigned short* __restrict__ Qp, const unsigned short* __restrict__ Kp,
    const unsigned short* __restrict__ Vt, unsigned short* __restrict__ Out) {
  constexpr int T = 2048, C = 2048;
  // LDS: K dbuf [2][64][128], V dbuf [2][128][64], P [4][32][64] = 80 KiB
  __shared__ unsigned short lds[40960];
  unsigned short* sP = lds + 32768;

  const int bid = blockIdx.x;
  const int swz = (bid & 7) * 64 + (bid >> 3);  // bijective, 512 % 8 == 0
  const int bh = swz >> 3;
  const int pr = swz & 7;                       // pair index
  const int b = bh >> 4, h = bh & 15;
  const int t = threadIdx.x, l = t & 63, w = t >> 6;
  const int lr = l & 15, lg = l >> 4, l7 = l & 7;

  const unsigned short* Kg = Kp + (size_t)(b * T) * C + h * 128;
  const unsigned short* Vg = Vt + ((size_t)bh << 18);  // [128][T]

  auto stage_kv = [&](int kb, int buf) {
    unsigned short* dK = lds + (buf ? 8192 : 0);
    unsigned short* dV = lds + 16384 + (buf ? 8192 : 0);
#pragma unroll
    for (int i = 0; i < 4; i++) {
      int c = t + i * 256;
      int row = c >> 4, cc = c & 15;
      LDS16(Kg + (size_t)(kb + row) * C + (cc ^ (row & 7)) * 8, &dK[c * 8]);
    }
#pragma unroll
    for (int i = 0; i < 4; i++) {
      int c = t + i * 256;
      int d = c >> 3, cc = c & 7;
      LDS16(Vg + (size_t)d * T + kb + (cc ^ (d & 7)) * 8, &dV[c * 8]);
    }
  };

  for (int seg = 0; seg < 2; seg++) {
    const int qt = seg ? pr : 15 - pr;  // heavy tile first
    const unsigned short* Qg = Qp + (size_t)(b * T + qt * 128) * C + h * 128;

#pragma unroll
    for (int i = 0; i < 8; i++) {
      int c = t + i * 256;
      int row = c >> 4, cc = c & 15;
      LDS16(Qg + (size_t)row * C + cc * 8, &lds[c * 8]);
    }
    __syncthreads();
    const int qw = qt * 128 + w * 32;
    short8 qf[2][4];
#pragma unroll
    for (int mi = 0; mi < 2; mi++)
#pragma unroll
      for (int ks = 0; ks < 4; ks++)
        qf[mi][ks] = *(const short8*)&lds[(w * 32 + mi * 16 + lr) * 128 +
                                          ks * 32 + lg * 8];
    __syncthreads();  // all qf reads done before K staging overwrites

    floatx4 zero = {0.f, 0.f, 0.f, 0.f};
    floatx4 oacc[2][8];
#pragma unroll
    for (int i = 0; i < 2; i++)
#pragma unroll
      for (int j = 0; j < 8; j++) oacc[i][j] = zero;
    float mold[2][4], lsum[2][4];
#pragma unroll
    for (int i = 0; i < 2; i++)
#pragma unroll
      for (int r = 0; r < 4; r++) { mold[i][r] = -1e30f; lsum[i][r] = 0.f; }

    const int ntile = 2 * qt + 2;
    stage_kv(0, 0);
    __syncthreads();
    int cur = 0;
    for (int tile = 0; tile < ntile; tile++) {
      const int kbase = tile * 64;
      if (tile + 1 < ntile) stage_kv(kbase + 64, cur ^ 1);  // async prefetch
      const unsigned short* sK = lds + (cur ? 8192 : 0);
      const unsigned short* sV = lds + 16384 + (cur ? 8192 : 0);
      if (kbase <= qw + 31) {
        // ---- S = Q K^T ----
        floatx4 sc[2][4];
#pragma unroll
        for (int i = 0; i < 2; i++)
#pragma unroll
          for (int j = 0; j < 4; j++) sc[i][j] = zero;
        __builtin_amdgcn_s_setprio(1);
#pragma unroll
        for (int ks = 0; ks < 4; ks++) {
#pragma unroll
          for (int ni = 0; ni < 4; ni++) {
            int R = ni * 16 + lr;
            short8 bF = *(const short8*)&sK[R * 128 + ((ks * 4 + lg) ^ l7) * 8];
#pragma unroll
            for (int mi = 0; mi < 2; mi++)
              sc[mi][ni] = mfma16(qf[mi][ks], bF, sc[mi][ni]);
          }
        }
        __builtin_amdgcn_s_setprio(0);
        // ---- causal mask (diagonal tiles only) ----
        if (kbase + 63 > qw) {
#pragma unroll
          for (int mi = 0; mi < 2; mi++)
#pragma unroll
            for (int ni = 0; ni < 4; ni++)
#pragma unroll
              for (int r = 0; r < 4; r++) {
                int col = kbase + ni * 16 + lr;
                int row = qw + mi * 16 + lg * 4 + r;
                if (col > row) sc[mi][ni][r] = -1e30f;
              }
        }
        // ---- online softmax (exp2 domain, defer-max THR=8) ----
#pragma unroll
        for (int mi = 0; mi < 2; mi++) {
          float xr[4];
          int dok = 1;
#pragma unroll
          for (int r = 0; r < 4; r++) {
            float x = fmaxf(fmaxf(sc[mi][0][r], sc[mi][1][r]),
                            fmaxf(sc[mi][2][r], sc[mi][3][r]));
            x = fmaxf(x, __shfl_xor(x, 1));
            x = fmaxf(x, __shfl_xor(x, 2));
            x = fmaxf(x, __shfl_xor(x, 4));
            x = fmaxf(x, __shfl_xor(x, 8));
            xr[r] = x;
            dok &= (x - mold[mi][r] <= 8.0f) ? 1 : 0;
          }
          const bool defer = __all(dok);  // wave-uniform
          float al[4];
          if (!defer) {
#pragma unroll
            for (int r = 0; r < 4; r++) {
              float m2 = fmaxf(mold[mi][r], xr[r]);
              al[r] = __builtin_amdgcn_exp2f(mold[mi][r] - m2);
              mold[mi][r] = m2;
            }
          }
          float rs[4] = {0.f, 0.f, 0.f, 0.f};
#pragma unroll
          for (int ni = 0; ni < 4; ni++)
#pragma unroll
            for (int r = 0; r < 4; r++) {
              float p = __builtin_amdgcn_exp2f(sc[mi][ni][r] - mold[mi][r]);
              sc[mi][ni][r] = p;
              rs[r] += p;
            }
#pragma unroll
          for (int r = 0; r < 4; r++) {
            float s = rs[r];
            s += __shfl_xor(s, 1);
            s += __shfl_xor(s, 2);
            s += __shfl_xor(s, 4);
            s += __shfl_xor(s, 8);
            rs[r] = s;
          }
          if (!defer) {
#pragma unroll
            for (int r = 0; r < 4; r++)
              lsum[mi][r] = lsum[mi][r] * al[r] + rs[r];
#pragma unroll
            for (int ni = 0; ni < 8; ni++)
#pragma unroll
              for (int r = 0; r < 4; r++) oacc[mi][ni][r] *= al[r];
          } else {
#pragma unroll
            for (int r = 0; r < 4; r++) lsum[mi][r] += rs[r];
          }
          // P -> bf16 -> swizzled per-wave LDS
#pragma unroll
          for (int ni = 0; ni < 4; ni++)
#pragma unroll
            for (int r = 0; r < 4; r++) {
              int rr = mi * 16 + lg * 4 + r;
              int ch = (ni * 2 + ((l >> 3) & 1)) ^ (rr & 7);
              sP[w * 2048 + rr * 64 + ch * 8 + l7] = f2bf(sc[mi][ni][r]);
            }
        }
        // ---- O += P V ----
        __builtin_amdgcn_s_setprio(1);
#pragma unroll
        for (int ks = 0; ks < 2; ks++) {
          short8 pf[2];
#pragma unroll
          for (int mi = 0; mi < 2; mi++)
            pf[mi] = *(const short8*)&sP[w * 2048 + (mi * 16 + lr) * 64 +
                                         ((ks * 4 + lg) ^ l7) * 8];
#pragma unroll
          for (int ni = 0; ni < 8; ni++) {
            int d = ni * 16 + lr;
            short8 vF = *(const short8*)&sV[d * 64 + ((ks * 4 + lg) ^ l7) * 8];
#pragma unroll
            for (int mi = 0; mi < 2; mi++)
              oacc[mi][ni] = mfma16(pf[mi], vF, oacc[mi][ni]);
          }
        }
        __builtin_amdgcn_s_setprio(0);
      }
      __syncthreads();  // drains prefetch vmcnt; next buffer ready
      cur ^= 1;
    }
    // ---- epilogue: O/l -> bf16 row-major [B*T, C] ----
    unsigned short* Og = Out + (size_t)(b * T + qw) * C + h * 128;
#pragma unroll
    for (int mi = 0; mi < 2; mi++) {
      float rl[4];
#pragma unroll
      for (int r = 0; r < 4; r++) rl[r] = 1.0f / lsum[mi][r];
#pragma unroll
      for (int ni = 0; ni < 8; ni++)
#pragma unroll
        for (int r = 0; r < 4; r++)
          Og[(size_t)(mi * 16 + lg * 4 + r) * C + ni * 16 + lr] =
              f2bf(oacc[mi][ni][r] * rl[r]);
    }
    __syncthreads();  // epilogue done before next segment's Q staging
  }
}

extern "C" void kernel_launch(void* const* d_in, const int* in_sizes, int n_in,
                              void* d_out, int out_size, void* d_ws,
                              size_t ws_size, hipStream_t stream) {
  const float* q = (const float*)d_in[0];
  const float* k = (const float*)d_in[1];
  const float* v = (const float*)d_in[2];
  const float* Wq = (const float*)d_in[3];
  const float* bq = (const float*)d_in[4];
  const float* Wk = (const float*)d_in[5];
  const float* bk = (const float*)d_in[6];
  const float* Wv = (const float*)d_in[7];
  const float* bv = (const float*)d_in[8];
  const float* Wo = (const float*)d_in[9];
  const float* bo = (const float*)d_in[10];

  const int B = 4, T = 2048, C = 2048;
  const size_t E = (size_t)B * T * C;   // 16,777,216
  const size_t WE = (size_t)C * C;      // 4,194,304
  unsigned short* ws = (unsigned short*)d_ws;
  unsigned short* qb = ws;              // bf16 q       [E]
  unsigned short* kb = ws + E;          // bf16 k
  unsigned short* vb = ws + 2 * E;      // bf16 v
  unsigned short* wqb = ws + 3 * E;     // bf16 weights [WE] x4
  unsigned short* wkb = wqb + WE;
  unsigned short* wvb = wqb + 2 * WE;
  unsigned short* wob = wqb + 3 * WE;
  unsigned short* Qp = ws + 4 * E;      // projected Q (pre-scaled)
  unsigned short* Kp = ws + 5 * E;      // projected K
  unsigned short* Vtb = ws + 6 * E;     // projected V, [B,H,D,T]
  unsigned short* attn = qb;            // alias: qb dead after projections
  // total workspace: 7*E*2 = 234,881,024 bytes

  Cvt7Args ca;
  ca.in[0] = q;  ca.out[0] = qb;  ca.n4[0] = (int)(E / 4);
  ca.in[1] = k;  ca.out[1] = kb;  ca.n4[1] = (int)(E / 4);
  ca.in[2] = v;  ca.out[2] = vb;  ca.n4[2] = (int)(E / 4);
  ca.in[3] = Wq; ca.out[3] = wqb; ca.n4[3] = (int)(WE / 4);
  ca.in[4] = Wk; ca.out[4] = wkb; ca.n4[4] = (int)(WE / 4);
  ca.in[5] = Wv; ca.out[5] = wvb; ca.n4[5] = (int)(WE / 4);
  ca.in[6] = Wo; ca.out[6] = wob; ca.n4[6] = (int)(WE / 4);
  cvt7_kernel<<<dim3(512, 7), 256, 0, stream>>>(ca);

  const float qscale = 1.4426950408889634f / sqrtf(128.0f);  // log2e/sqrt(D)
  gemm256_proj3<<<768, 512, 0, stream>>>(qb, kb, vb, wqb, wkb, wvb, bq, bk, bv,
                                         Qp, Kp, Vtb, qscale);

  attn_kernel<<<512, 256, 0, stream>>>(Qp, Kp, Vtb, attn);

  gemm256_out<<<256, 512, 0, stream>>>(attn, wob, bo, (float*)d_out);
}